// Round 3
// baseline (1655.170 us; speedup 1.0000x reference)
//
#include <hip/hip_runtime.h>
#include <cstdint>
#include <cstddef>

#define B_ 2048
#define N_ 256

typedef unsigned short u16;
typedef unsigned int u32;
typedef __attribute__((ext_vector_type(8))) short short8;
typedef __attribute__((ext_vector_type(4))) float floatx4;

__device__ __forceinline__ u16 f2bf(float f) {
  union { float f; unsigned u; } v; v.f = f;
  unsigned u = v.u;
  return (u16)((u + 0x7FFFu + ((u >> 16) & 1u)) >> 16);
}
// single-instruction RNE pack of 2 f32 -> 2 bf16 (low=a, high=b)
__device__ __forceinline__ u32 cvt_pk_bf16(float a, float b) {
  u32 r;
  asm("v_cvt_pk_bf16_f32 %0, %1, %2" : "=v"(r) : "v"(a), "v"(b));
  return r;
}
__device__ __forceinline__ float tanh_fast(float x) {
  x = fmaxf(fminf(x, 30.0f), -30.0f);
  float u = __expf(-2.0f * x);
  return __fdividef(1.0f - u, 1.0f + u);
}

// ---------------- combined weight packer: both blobs in one launch.
// frag order: elem = ((nt*ks + ksi)*64 + lane)*8 + j -> W[ksi*32+(lane>>4)*8+j][nt*16+(lane&15)]
__global__ void rlp_pack_all(const float* __restrict__ dw0, const float* __restrict__ dw1,
                             const float* __restrict__ dw2, const float* __restrict__ dw3,
                             const float* __restrict__ ew0, const float* __restrict__ ew1,
                             const float* __restrict__ ew2, const float* __restrict__ ew3,
                             u16* __restrict__ wdyn, u16* __restrict__ wdec) {
  int e = blockIdx.x * blockDim.x + threadIdx.x;
  const float* W; int K, Nc, ks, base; u16* dst;
  if (e < 20480)       { W = dw0; K = 145; Nc = 128; ks = 5; dst = wdyn;         base = 0; }
  else if (e < 36864)  { W = dw1; K = 128; Nc = 128; ks = 4; dst = wdyn + 20480; base = 20480; }
  else if (e < 53248)  { W = dw2; K = 128; Nc = 128; ks = 4; dst = wdyn + 36864; base = 36864; }
  else if (e < 61440)  { W = dw3; K = 128; Nc = 64;  ks = 4; dst = wdyn + 53248; base = 53248; }
  else if (e < 69632)  { W = ew0; K = 64;  Nc = 128; ks = 2; dst = wdec;         base = 61440; }
  else if (e < 86016)  { W = ew1; K = 128; Nc = 128; ks = 4; dst = wdec + 8192;  base = 69632; }
  else if (e < 102400) { W = ew2; K = 128; Nc = 128; ks = 4; dst = wdec + 24576; base = 86016; }
  else if (e < 104448) { W = ew3; K = 128; Nc = 14;  ks = 4; dst = wdec + 40960; base = 102400; }
  else return;
  int el = e - base;
  int j = el & 7;
  int lane = (el >> 3) & 63;
  int tt = el >> 9;
  int ksi = tt % ks;
  int nt = tt / ks;
  int col = nt * 16 + (lane & 15);
  int k = ksi * 32 + ((lane >> 4) << 3) + j;
  float v = 0.0f;
  if (k < K && col < Nc) v = W[k * Nc + col];
  dst[el] = f2bf(v);
}

// ---------------- one hidden layer (swapped MFMA, A=W frags in VGPR, B=x frags from LDS).
// KSD = dynamic (LDS-read) k-steps, KS-KSD static frags from xstat. Single barrier LN.
template <int KS, int KSD, int NROW, int SSTR, int DSTR>
__device__ __forceinline__ void mlp_layer(
    const short8 (&wf)[KS], const short8* xstat,
    floatx4 bv, floatx4 gv, floatx4 ev,
    const u16* src, u16* dst, float* lnbuf, int wv, int lane) {
  const int rrow = lane & 15;
  const int g = lane >> 4;
  const int srow = (NROW == 4) ? (rrow & 3) : rrow;
  short8 xf[KSD];
#pragma unroll
  for (int ks = 0; ks < KSD; ks++)
    xf[ks] = *reinterpret_cast<const short8*>(&src[srow * SSTR + ks * 32 + g * 8]);
  floatx4 acc = bv;
#pragma unroll
  for (int ks = 0; ks < KSD; ks++)
    acc = __builtin_amdgcn_mfma_f32_16x16x32_bf16(wf[ks], xf[ks], acc, 0, 0, 0);
#pragma unroll
  for (int ks = KSD; ks < KS; ks++)
    acc = __builtin_amdgcn_mfma_f32_16x16x32_bf16(wf[ks], xstat[ks - KSD], acc, 0, 0, 0);
  float s = acc[0] + acc[1] + acc[2] + acc[3];
  float q = acc[0] * acc[0] + acc[1] * acc[1] + acc[2] * acc[2] + acc[3] * acc[3];
  s += __shfl_xor(s, 16, 64); q += __shfl_xor(q, 16, 64);
  s += __shfl_xor(s, 32, 64); q += __shfl_xor(q, 32, 64);
  if (lane < NROW) {
    *reinterpret_cast<float2*>(&lnbuf[lane * 20 + 2 * wv]) = make_float2(s, q);
  }
  __syncthreads();
  floatx4 p0 = *reinterpret_cast<const floatx4*>(&lnbuf[srow * 20 + 0]);
  floatx4 p1 = *reinterpret_cast<const floatx4*>(&lnbuf[srow * 20 + 4]);
  floatx4 p2 = *reinterpret_cast<const floatx4*>(&lnbuf[srow * 20 + 8]);
  floatx4 p3 = *reinterpret_cast<const floatx4*>(&lnbuf[srow * 20 + 12]);
  float S = p0[0] + p0[2] + p1[0] + p1[2] + p2[0] + p2[2] + p3[0] + p3[2];
  float Q = p0[1] + p0[3] + p1[1] + p1[3] + p2[1] + p2[3] + p3[1] + p3[3];
  float mean = S * (1.0f / 128.0f);
  float rs = rsqrtf(Q * (1.0f / 128.0f) - mean * mean + 1e-5f);
  float h0 = tanh_fast((acc[0] - mean) * rs * gv[0] + ev[0]);
  float h1 = tanh_fast((acc[1] - mean) * rs * gv[1] + ev[1]);
  float h2 = tanh_fast((acc[2] - mean) * rs * gv[2] + ev[2]);
  float h3 = tanh_fast((acc[3] - mean) * rs * gv[3] + ev[3]);
  if (rrow < NROW) {
    int f = 16 * wv + 4 * g;
    uint2 hp = make_uint2(cvt_pk_bf16(h0, h1), cvt_pk_bf16(h2, h3));
    *reinterpret_cast<uint2*>(&dst[rrow * DSTR + f]) = hp;
  }
  __syncthreads();
}

// ---------------- scan: 512 threads (8 waves), 4 batch rows per WG (grid 512 -> 2 blocks/CU),
// weights in VGPRs, z in registers of waves 0-3; waves 4-7 prep next-step Fourier embedding.
// Also computes ctx encoder + z0 encoder in-WG (no separate kernels).
__global__ __launch_bounds__(512, 4) void rlp_scan3(
    const float* __restrict__ t, const u16* __restrict__ wdyn,
    const float* __restrict__ ctxg, const float* __restrict__ cew,
    const float* __restrict__ ceb, const float* __restrict__ z0w,
    const float* __restrict__ z0b,
    const float* __restrict__ db0, const float* __restrict__ db1,
    const float* __restrict__ db2, const float* __restrict__ db3,
    const float* __restrict__ dg0, const float* __restrict__ dbe0,
    const float* __restrict__ dg1, const float* __restrict__ dbe1,
    const float* __restrict__ dg2, const float* __restrict__ dbe2,
    u16* __restrict__ ztraj, int b0) {
  __shared__ __align__(16) u16 xb[4][160];   // 0-63 z | 64-80 temb | 81-144 ctx | 145-159 zero
  __shared__ __align__(16) u16 hA[4][160];
  __shared__ __align__(16) u16 hB[4][160];
  __shared__ __align__(16) float lnS[4 * 20];
  __shared__ float ctxe[4][64];
  __shared__ float zbuf[4][64];
  __shared__ float dts[2][4];

  const int tid = threadIdx.x;
  const int wv = tid >> 6;
  const int lane = tid & 63;
  const int rrow = lane & 15;
  const int g = lane >> 4;
  const int r4 = rrow & 3;
  const int w4 = wv & 3;
  const int fb = 16 * wv + 4 * g;
  const int fb4 = 16 * w4 + 4 * g;
  const int gb = b0 + blockIdx.x * 4;

  const floatx4 b1 = *(const floatx4*)&db0[fb];
  const floatx4 g1 = *(const floatx4*)&dg0[fb];
  const floatx4 e1 = *(const floatx4*)&dbe0[fb];
  const floatx4 b2 = *(const floatx4*)&db1[fb];
  const floatx4 g2 = *(const floatx4*)&dg1[fb];
  const floatx4 e2 = *(const floatx4*)&dbe1[fb];
  const floatx4 b3 = *(const floatx4*)&db2[fb];
  const floatx4 g3 = *(const floatx4*)&dg2[fb];
  const floatx4 e3 = *(const floatx4*)&dbe2[fb];
  const floatx4 b4 = *(const floatx4*)&db3[fb4];

  short8 wf1[5], wf2[4], wf3[4], wf4[4];
#pragma unroll
  for (int ks = 0; ks < 5; ks++)
    wf1[ks] = *(const short8*)(wdyn + ((size_t)(wv * 5 + ks) * 64 + lane) * 8);
#pragma unroll
  for (int ks = 0; ks < 4; ks++)
    wf2[ks] = *(const short8*)(wdyn + 20480 + ((size_t)(wv * 4 + ks) * 64 + lane) * 8);
#pragma unroll
  for (int ks = 0; ks < 4; ks++)
    wf3[ks] = *(const short8*)(wdyn + 36864 + ((size_t)(wv * 4 + ks) * 64 + lane) * 8);
#pragma unroll
  for (int ks = 0; ks < 4; ks++)
    wf4[ks] = *(const short8*)(wdyn + 53248 + ((size_t)(w4 * 4 + ks) * 64 + lane) * 8);

  // zero xb (incl. the 145-159 pad); hA/hB are fully written before read, no init needed
  for (int i = tid; i < 320; i += 512) reinterpret_cast<u32*>(&xb[0][0])[i] = 0;
  __syncthreads();

  // ctx encoder: ctx_emb = tanh(context @ ce_w + ce_b) for our 4 rows
  if (tid < 256) {
    int b = tid >> 6, c = tid & 63;
    float s = ceb[c];
#pragma unroll
    for (int k = 0; k < 32; k++) s += ctxg[(size_t)(gb + b) * 32 + k] * cew[k * 64 + c];
    float v = tanh_fast(s);
    ctxe[b][c] = v;
    xb[b][81 + c] = f2bf(v);
  } else {
    int t2 = tid - 256;
    if (t2 < 68) {
      int b = t2 / 17, j = t2 - b * 17;
      float tv = t[(size_t)(gb + b) * N_];
      float val = (j == 0) ? tv
                : (j <= 8 ? __sinf(tv * (3.14159265358979f * (float)(1 << (j - 1))))
                          : __cosf(tv * (3.14159265358979f * (float)(1 << (j - 9)))));
      xb[b][64 + j] = f2bf(val);
    }
    if (t2 >= 68 && t2 < 72) {
      int b = t2 - 68;
      dts[0][b] = t[(size_t)(gb + b) * N_ + 1] - t[(size_t)(gb + b) * N_];
    }
  }
  __syncthreads();
  // z0 encoder: z0 = tanh(ctx_emb @ z0_w + z0_b)
  if (tid < 256) {
    int b = tid >> 6, l = tid & 63;
    float s = z0b[l];
#pragma unroll 8
    for (int k = 0; k < 64; k++) s += ctxe[b][k] * z0w[k * 64 + l];
    zbuf[b][l] = tanh_fast(s);
  }
  __syncthreads();
  float zr0, zr1, zr2, zr3;
  {
    const floatx4 zv = *(const floatx4*)&zbuf[r4][fb4];
    zr0 = zv[0]; zr1 = zv[1]; zr2 = zv[2]; zr3 = zv[3];
    if (wv < 4 && rrow < 4) {
      uint2 zp = make_uint2(cvt_pk_bf16(zr0, zr1), cvt_pk_bf16(zr2, zr3));
      *reinterpret_cast<uint2*>(&xb[rrow][fb4]) = zp;
      size_t zi = ((size_t)(blockIdx.x * 4 + rrow) * N_) * 64 + fb4;
      *reinterpret_cast<uint2*>(&ztraj[zi]) = zp;
    }
  }
  __syncthreads();

  // loop-invariant L1 fragments (cols 96-159: static ctx + zero pad)
  short8 xs[2];
  xs[0] = *reinterpret_cast<const short8*>(&xb[r4][96 + g * 8]);
  xs[1] = *reinterpret_cast<const short8*>(&xb[r4][128 + g * 8]);

  for (int n = 0; n < N_ - 1; n++) {
    mlp_layer<5, 3, 4, 160, 160>(wf1, xs, b1, g1, e1, &xb[0][0], &hA[0][0], lnS, wv, lane);
    mlp_layer<4, 4, 4, 160, 160>(wf2, nullptr, b2, g2, e2, &hA[0][0], &hB[0][0], lnS, wv, lane);
    mlp_layer<4, 4, 4, 160, 160>(wf3, nullptr, b3, g3, e3, &hB[0][0], &hA[0][0], lnS, wv, lane);
    if (wv < 4) {
      short8 xf[4];
#pragma unroll
      for (int ks = 0; ks < 4; ks++)
        xf[ks] = *reinterpret_cast<const short8*>(&hA[r4][ks * 32 + g * 8]);
      floatx4 da = b4;
#pragma unroll
      for (int ks = 0; ks < 4; ks++)
        da = __builtin_amdgcn_mfma_f32_16x16x32_bf16(wf4[ks], xf[ks], da, 0, 0, 0);
      float dt = dts[n & 1][r4];
      zr0 += dt * da[0]; zr1 += dt * da[1]; zr2 += dt * da[2]; zr3 += dt * da[3];
      if (rrow < 4) {
        uint2 zp = make_uint2(cvt_pk_bf16(zr0, zr1), cvt_pk_bf16(zr2, zr3));
        *reinterpret_cast<uint2*>(&xb[rrow][fb4]) = zp;
        size_t zi = ((size_t)(blockIdx.x * 4 + rrow) * N_ + (n + 1)) * 64 + fb4;
        *reinterpret_cast<uint2*>(&ztraj[zi]) = zp;
      }
    } else {
      int t2 = tid - 256;
      if (n < N_ - 2) {
        if (t2 < 68) {
          int b = t2 / 17, j = t2 - b * 17;
          float tv = t[(size_t)(gb + b) * N_ + n + 1];
          float val = (j == 0) ? tv
                    : (j <= 8 ? __sinf(tv * (3.14159265358979f * (float)(1 << (j - 1))))
                              : __cosf(tv * (3.14159265358979f * (float)(1 << (j - 9)))));
          xb[b][64 + j] = f2bf(val);
        }
        if (t2 >= 68 && t2 < 72) {
          int b = t2 - 68;
          dts[(n + 1) & 1][b] =
              t[(size_t)(gb + b) * N_ + n + 2] - t[(size_t)(gb + b) * N_ + n + 1];
        }
      }
    }
    __syncthreads();
  }
}

// ---------------- decoder: 512 threads (8 waves), weights in VGPRs, 16 rows/iter,
// grid-stride persistent; coalesced output flush staged via LDS.
__global__ __launch_bounds__(512, 4) void rlp_dec3(
    const u16* __restrict__ wdec, const u16* __restrict__ ztraj,
    const float* __restrict__ eb0, const float* __restrict__ eb1,
    const float* __restrict__ eb2, const float* __restrict__ eb3,
    const float* __restrict__ eg0, const float* __restrict__ ebe0,
    const float* __restrict__ eg1, const float* __restrict__ ebe1,
    const float* __restrict__ eg2, const float* __restrict__ ebe2,
    float* __restrict__ out, int b0, int nrows) {
  __shared__ __align__(16) u16 xz[16][72];
  __shared__ __align__(16) u16 hA[16][136];
  __shared__ __align__(16) u16 hB[16][136];
  __shared__ __align__(16) float lnD[16 * 20];
  __shared__ float obuf[224];
  __shared__ float bias1[128], bias2[128], bias3[128], bias4[16];
  __shared__ float g1s[128], e1s[128], g2s[128], e2s[128], g3s[128], e3s[128];

  const int tid = threadIdx.x;
  const int wv = tid >> 6;
  const int lane = tid & 63;
  const int rrow = lane & 15;
  const int g = lane >> 4;
  const int fb = 16 * wv + 4 * g;

  short8 wf1[2], wf2[4], wf3[4], wf4[4];
#pragma unroll
  for (int ks = 0; ks < 2; ks++)
    wf1[ks] = *(const short8*)(wdec + ((size_t)(wv * 2 + ks) * 64 + lane) * 8);
#pragma unroll
  for (int ks = 0; ks < 4; ks++)
    wf2[ks] = *(const short8*)(wdec + 8192 + ((size_t)(wv * 4 + ks) * 64 + lane) * 8);
#pragma unroll
  for (int ks = 0; ks < 4; ks++)
    wf3[ks] = *(const short8*)(wdec + 24576 + ((size_t)(wv * 4 + ks) * 64 + lane) * 8);
#pragma unroll
  for (int ks = 0; ks < 4; ks++)
    wf4[ks] = *(const short8*)(wdec + 40960 + ((size_t)ks * 64 + lane) * 8);

  for (int i = tid; i < 128; i += 512) {
    bias1[i] = eb0[i]; bias2[i] = eb1[i]; bias3[i] = eb2[i];
    g1s[i] = eg0[i]; e1s[i] = ebe0[i];
    g2s[i] = eg1[i]; e2s[i] = ebe1[i];
    g3s[i] = eg2[i]; e3s[i] = ebe2[i];
  }
  if (tid < 16) bias4[tid] = (tid < 14) ? eb3[tid] : 0.0f;
  __syncthreads();

  const floatx4 b1 = *(const floatx4*)&bias1[fb];
  const floatx4 g1v = *(const floatx4*)&g1s[fb];
  const floatx4 e1v = *(const floatx4*)&e1s[fb];
  const floatx4 b2 = *(const floatx4*)&bias2[fb];
  const floatx4 g2v = *(const floatx4*)&g2s[fb];
  const floatx4 e2v = *(const floatx4*)&e2s[fb];
  const floatx4 b3 = *(const floatx4*)&bias3[fb];
  const floatx4 g3v = *(const floatx4*)&g3s[fb];
  const floatx4 e3v = *(const floatx4*)&e3s[fb];
  const floatx4 b4 = *(const floatx4*)&bias4[4 * g];

  const int ntiles = nrows >> 4;
  int prevbase = -1;
  for (int tile = blockIdx.x; tile < ntiles; tile += gridDim.x) {
    if (prevbase >= 0 && tid < 224) out[prevbase + tid] = obuf[tid];
    if (tid < 128) {
      int rr = tid >> 3, p = tid & 7;
      *reinterpret_cast<short8*>(&xz[rr][p * 8]) =
          *reinterpret_cast<const short8*>(&ztraj[(size_t)(tile * 16 + rr) * 64 + p * 8]);
    }
    __syncthreads();
    mlp_layer<2, 2, 16, 72, 136>(wf1, nullptr, b1, g1v, e1v, &xz[0][0], &hA[0][0], lnD, wv, lane);
    mlp_layer<4, 4, 16, 136, 136>(wf2, nullptr, b2, g2v, e2v, &hA[0][0], &hB[0][0], lnD, wv, lane);
    mlp_layer<4, 4, 16, 136, 136>(wf3, nullptr, b3, g3v, e3v, &hB[0][0], &hA[0][0], lnD, wv, lane);
    if (wv == 0) {
      short8 xf[4];
#pragma unroll
      for (int ks = 0; ks < 4; ks++)
        xf[ks] = *reinterpret_cast<const short8*>(&hA[rrow][ks * 32 + g * 8]);
      floatx4 da = b4;
#pragma unroll
      for (int ks = 0; ks < 4; ks++)
        da = __builtin_amdgcn_mfma_f32_16x16x32_bf16(wf4[ks], xf[ks], da, 0, 0, 0);
#pragma unroll
      for (int r = 0; r < 4; r++) {
        int wc = 4 * g + r;
        if (wc < 14) obuf[rrow * 14 + wc] = da[r];
      }
    }
    __syncthreads();
    prevbase = b0 * 3584 + tile * 224;
  }
  if (prevbase >= 0 && tid < 224) out[prevbase + tid] = obuf[tid];
}

extern "C" void kernel_launch(void* const* d_in, const int* in_sizes, int n_in,
                              void* d_out, int out_size, void* d_ws, size_t ws_size,
                              hipStream_t stream) {
  const float* t = (const float*)d_in[0];
  const float* ctx = (const float*)d_in[1];
  const float* ce_w = (const float*)d_in[2];
  const float* ce_b = (const float*)d_in[3];
  const float* z0_w = (const float*)d_in[4];
  const float* z0_b = (const float*)d_in[5];
  const float* dw0 = (const float*)d_in[6];
  const float* db0 = (const float*)d_in[7];
  const float* dw1 = (const float*)d_in[8];
  const float* db1 = (const float*)d_in[9];
  const float* dw2 = (const float*)d_in[10];
  const float* db2 = (const float*)d_in[11];
  const float* dw3 = (const float*)d_in[12];
  const float* db3 = (const float*)d_in[13];
  const float* dg0 = (const float*)d_in[14];
  const float* dbe0 = (const float*)d_in[15];
  const float* dg1 = (const float*)d_in[16];
  const float* dbe1 = (const float*)d_in[17];
  const float* dg2 = (const float*)d_in[18];
  const float* dbe2 = (const float*)d_in[19];
  const float* ew0 = (const float*)d_in[20];
  const float* eb0 = (const float*)d_in[21];
  const float* ew1 = (const float*)d_in[22];
  const float* eb1 = (const float*)d_in[23];
  const float* ew2 = (const float*)d_in[24];
  const float* eb2 = (const float*)d_in[25];
  const float* ew3 = (const float*)d_in[26];
  const float* eb3 = (const float*)d_in[27];
  const float* eg0 = (const float*)d_in[28];
  const float* ebe0 = (const float*)d_in[29];
  const float* eg1 = (const float*)d_in[30];
  const float* ebe1 = (const float*)d_in[31];
  const float* eg2 = (const float*)d_in[32];
  const float* ebe2 = (const float*)d_in[33];
  float* out = (float*)d_out;

  char* ws = (char*)d_ws;
  u16* wdyn = (u16*)(ws + 0);            // 61440 elems = 122880 B
  u16* wdec = (u16*)(ws + 122880);       // 43008 elems =  86016 B
  u16* zt = (u16*)(ws + 208896);         // z_traj bf16
  size_t zt_avail = (ws_size > 208896) ? ws_size - 208896 : 0;

  rlp_pack_all<<<408, 256, 0, stream>>>(dw0, dw1, dw2, dw3, ew0, ew1, ew2, ew3, wdyn, wdec);

  const size_t per_row = (size_t)N_ * 64 * 2;
  int chunkB = B_;
  if (zt_avail < (size_t)B_ * per_row) {
    chunkB = (int)(zt_avail / per_row) & ~3;
    if (chunkB < 4) chunkB = 4;
  }
  for (int b0 = 0; b0 < B_; b0 += chunkB) {
    int cb = (B_ - b0 < chunkB) ? (B_ - b0) : chunkB;
    rlp_scan3<<<cb / 4, 512, 0, stream>>>(t, wdyn, ctx, ce_w, ce_b, z0_w, z0_b,
        db0, db1, db2, db3, dg0, dbe0, dg1, dbe1, dg2, dbe2, zt, b0);
    int ntiles = cb * 16;
    int ngrid = ntiles < 1024 ? ntiles : 1024;
    rlp_dec3<<<ngrid, 512, 0, stream>>>(wdec, zt,
        eb0, eb1, eb2, eb3, eg0, ebe0, eg1, ebe1, eg2, ebe2, out, b0, cb * 256);
  }
}

// Round 4
// 1026.128 us; speedup vs baseline: 1.6130x; 1.6130x over previous
//
#include <hip/hip_runtime.h>
#include <cstdint>
#include <cstddef>

#define B_ 2048
#define N_ 256

typedef unsigned short u16;
typedef unsigned int u32;
typedef __attribute__((ext_vector_type(8))) short short8;
typedef __attribute__((ext_vector_type(4))) float floatx4;

__device__ __forceinline__ u16 f2bf(float f) {
  union { float f; unsigned u; } v; v.f = f;
  unsigned u = v.u;
  return (u16)((u + 0x7FFFu + ((u >> 16) & 1u)) >> 16);
}
// single-instruction RNE pack of 2 f32 -> 2 bf16 (low=a, high=b)
__device__ __forceinline__ u32 cvt_pk_bf16(float a, float b) {
  u32 r;
  asm("v_cvt_pk_bf16_f32 %0, %1, %2" : "=v"(r) : "v"(a), "v"(b));
  return r;
}
__device__ __forceinline__ float tanh_fast(float x) {
  x = fmaxf(fminf(x, 30.0f), -30.0f);
  float u = __expf(-2.0f * x);
  return __fdividef(1.0f - u, 1.0f + u);
}

// ---------------- combined weight packer (one launch).
// frag order: elem = ((nt*ks + ksi)*64 + lane)*8 + j -> W[ksi*32+(lane>>4)*8+j][nt*16+(lane&15)]
__global__ void rlp_pack_all(const float* __restrict__ dw0, const float* __restrict__ dw1,
                             const float* __restrict__ dw2, const float* __restrict__ dw3,
                             const float* __restrict__ ew0, const float* __restrict__ ew1,
                             const float* __restrict__ ew2, const float* __restrict__ ew3,
                             u16* __restrict__ wdyn, u16* __restrict__ wdec) {
  int e = blockIdx.x * blockDim.x + threadIdx.x;
  const float* W; int K, Nc, ks, base; u16* dst;
  if (e < 20480)       { W = dw0; K = 145; Nc = 128; ks = 5; dst = wdyn;         base = 0; }
  else if (e < 36864)  { W = dw1; K = 128; Nc = 128; ks = 4; dst = wdyn + 20480; base = 20480; }
  else if (e < 53248)  { W = dw2; K = 128; Nc = 128; ks = 4; dst = wdyn + 36864; base = 36864; }
  else if (e < 61440)  { W = dw3; K = 128; Nc = 64;  ks = 4; dst = wdyn + 53248; base = 53248; }
  else if (e < 69632)  { W = ew0; K = 64;  Nc = 128; ks = 2; dst = wdec;         base = 61440; }
  else if (e < 86016)  { W = ew1; K = 128; Nc = 128; ks = 4; dst = wdec + 8192;  base = 69632; }
  else if (e < 102400) { W = ew2; K = 128; Nc = 128; ks = 4; dst = wdec + 24576; base = 86016; }
  else if (e < 104448) { W = ew3; K = 128; Nc = 14;  ks = 4; dst = wdec + 40960; base = 102400; }
  else return;
  int el = e - base;
  int j = el & 7;
  int lane = (el >> 3) & 63;
  int tt = el >> 9;
  int ksi = tt % ks;
  int nt = tt / ks;
  int col = nt * 16 + (lane & 15);
  int k = ksi * 32 + ((lane >> 4) << 3) + j;
  float v = 0.0f;
  if (k < K && col < Nc) v = W[k * Nc + col];
  dst[el] = f2bf(v);
}

// ---------------- one hidden layer (swapped MFMA: A=W frag in VGPR/AGPR, B=x frag from LDS).
// C[m=wcol][n=brow]: lane&15 = brow, (lane>>4)*4+r = wcol-within-tile.
// KSD dynamic (LDS) k-steps + (KS-KSD) static frags. 2 barriers: LN partial exchange + h publish.
template <int KS, int KSD, int NROW, int SSTR, int DSTR>
__device__ __forceinline__ void mlp_layer(
    const short8 (&wf)[KS], const short8* xstat,
    floatx4 bv, floatx4 gv, floatx4 ev,
    const u16* src, u16* dst, float* lnbuf, int wv, int lane) {
  const int rrow = lane & 15;          // batch row (B-col of MFMA)
  const int g = lane >> 4;
  const int srow = (NROW == 8) ? (rrow & 7) : rrow;
  short8 xf[KSD];
#pragma unroll
  for (int ks = 0; ks < KSD; ks++)
    xf[ks] = *reinterpret_cast<const short8*>(&src[srow * SSTR + ks * 32 + g * 8]);
  floatx4 acc = bv;
#pragma unroll
  for (int ks = 0; ks < KSD; ks++)
    acc = __builtin_amdgcn_mfma_f32_16x16x32_bf16(wf[ks], xf[ks], acc, 0, 0, 0);
#pragma unroll
  for (int ks = KSD; ks < KS; ks++)
    acc = __builtin_amdgcn_mfma_f32_16x16x32_bf16(wf[ks], xstat[ks - KSD], acc, 0, 0, 0);
  // per-brow partial sums over this wave's 16 wcols
  float s = acc[0] + acc[1] + acc[2] + acc[3];
  float q = acc[0] * acc[0] + acc[1] * acc[1] + acc[2] * acc[2] + acc[3] * acc[3];
  s += __shfl_xor(s, 16, 64); q += __shfl_xor(q, 16, 64);
  s += __shfl_xor(s, 32, 64); q += __shfl_xor(q, 32, 64);
  if (lane < NROW) {
    *reinterpret_cast<float2*>(&lnbuf[lane * 20 + 2 * wv]) = make_float2(s, q);
  }
  __syncthreads();
  floatx4 p0 = *reinterpret_cast<const floatx4*>(&lnbuf[srow * 20 + 0]);
  floatx4 p1 = *reinterpret_cast<const floatx4*>(&lnbuf[srow * 20 + 4]);
  floatx4 p2 = *reinterpret_cast<const floatx4*>(&lnbuf[srow * 20 + 8]);
  floatx4 p3 = *reinterpret_cast<const floatx4*>(&lnbuf[srow * 20 + 12]);
  float S = p0[0] + p0[2] + p1[0] + p1[2] + p2[0] + p2[2] + p3[0] + p3[2];
  float Q = p0[1] + p0[3] + p1[1] + p1[3] + p2[1] + p2[3] + p3[1] + p3[3];
  float mean = S * (1.0f / 128.0f);
  float rs = rsqrtf(Q * (1.0f / 128.0f) - mean * mean + 1e-5f);
  float h0 = tanh_fast((acc[0] - mean) * rs * gv[0] + ev[0]);
  float h1 = tanh_fast((acc[1] - mean) * rs * gv[1] + ev[1]);
  float h2 = tanh_fast((acc[2] - mean) * rs * gv[2] + ev[2]);
  float h3 = tanh_fast((acc[3] - mean) * rs * gv[3] + ev[3]);
  if (rrow < NROW) {
    int f = 16 * wv + 4 * g;
    uint2 hp = make_uint2(cvt_pk_bf16(h0, h1), cvt_pk_bf16(h2, h3));
    *reinterpret_cast<uint2*>(&dst[rrow * DSTR + f]) = hp;
  }
  __syncthreads();
}

// ---------------- scan: 512 threads (8 waves), 8 batch rows per WG, grid 256 (1 WG/CU).
// Weights in registers; t preloaded to LDS; z state in registers of waves 0-3;
// waves 4-7 compute next-step Fourier embedding concurrently with L4.
__global__ __launch_bounds__(512, 1) void rlp_scan4(
    const float* __restrict__ t, const u16* __restrict__ wdyn,
    const float* __restrict__ ctxg, const float* __restrict__ cew,
    const float* __restrict__ ceb, const float* __restrict__ z0w,
    const float* __restrict__ z0b,
    const float* __restrict__ db0, const float* __restrict__ db1,
    const float* __restrict__ db2, const float* __restrict__ db3,
    const float* __restrict__ dg0, const float* __restrict__ dbe0,
    const float* __restrict__ dg1, const float* __restrict__ dbe1,
    const float* __restrict__ dg2, const float* __restrict__ dbe2,
    u16* __restrict__ ztraj, int b0) {
  __shared__ __align__(16) u16 xb[8][168];   // 0-63 z | 64-80 temb | 81-144 ctx | 145-167 zero
  __shared__ __align__(16) u16 hA[8][168];
  __shared__ __align__(16) u16 hB[8][168];
  __shared__ __align__(16) float lnS[8 * 20];
  __shared__ __align__(16) float tl[8][260];  // padded stride: banks spread (260%32=4)
  __shared__ float ctxe[8][64];
  __shared__ float zbuf[8][64];

  const int tid = threadIdx.x;
  const int wv = tid >> 6;
  const int lane = tid & 63;
  const int rrow = lane & 15;
  const int g = lane >> 4;
  const int r8 = rrow & 7;
  const int w4 = wv & 3;
  const int fb = 16 * wv + 4 * g;
  const int fb4 = 16 * w4 + 4 * g;
  const int gb = b0 + blockIdx.x * 8;

  const floatx4 b1 = *(const floatx4*)&db0[fb];
  const floatx4 g1 = *(const floatx4*)&dg0[fb];
  const floatx4 e1 = *(const floatx4*)&dbe0[fb];
  const floatx4 b2 = *(const floatx4*)&db1[fb];
  const floatx4 g2 = *(const floatx4*)&dg1[fb];
  const floatx4 e2 = *(const floatx4*)&dbe1[fb];
  const floatx4 b3 = *(const floatx4*)&db2[fb];
  const floatx4 g3 = *(const floatx4*)&dg2[fb];
  const floatx4 e3 = *(const floatx4*)&dbe2[fb];
  const floatx4 b4 = *(const floatx4*)&db3[fb4];

  short8 wf1[5], wf2[4], wf3[4], wf4[4];
#pragma unroll
  for (int ks = 0; ks < 5; ks++)
    wf1[ks] = *(const short8*)(wdyn + ((size_t)(wv * 5 + ks) * 64 + lane) * 8);
#pragma unroll
  for (int ks = 0; ks < 4; ks++)
    wf2[ks] = *(const short8*)(wdyn + 20480 + ((size_t)(wv * 4 + ks) * 64 + lane) * 8);
#pragma unroll
  for (int ks = 0; ks < 4; ks++)
    wf3[ks] = *(const short8*)(wdyn + 36864 + ((size_t)(wv * 4 + ks) * 64 + lane) * 8);
#pragma unroll
  for (int ks = 0; ks < 4; ks++)
    wf4[ks] = *(const short8*)(wdyn + 53248 + ((size_t)(w4 * 4 + ks) * 64 + lane) * 8);

  // t -> LDS (coalesced) and zero xb
  for (int i = tid; i < 8 * 256; i += 512) {
    int r = i >> 8, c = i & 255;
    tl[r][c] = t[(size_t)(gb + r) * N_ + c];
  }
  for (int i = tid; i < 8 * 168 / 2; i += 512) reinterpret_cast<u32*>(&xb[0][0])[i] = 0;
  __syncthreads();

  // ctx encoder: 8 rows x 64 cols over all 512 threads
  {
    int b = tid >> 6, c = tid & 63;
    float s = ceb[c];
#pragma unroll
    for (int k = 0; k < 32; k++) s += ctxg[(size_t)(gb + b) * 32 + k] * cew[k * 64 + c];
    float v = tanh_fast(s);
    ctxe[b][c] = v;
    xb[b][81 + c] = f2bf(v);
  }
  __syncthreads();
  // z0 encoder
  {
    int b = tid >> 6, l = tid & 63;
    float s = z0b[l];
#pragma unroll 8
    for (int k = 0; k < 64; k++) s += ctxe[b][k] * z0w[k * 64 + l];
    zbuf[b][l] = tanh_fast(s);
  }
  // temb(0)
  if (tid < 136) {
    int b = tid / 17, j = tid - b * 17;
    float tv = tl[b][0];
    float val = (j == 0) ? tv
              : (j <= 8 ? __sinf(tv * (3.14159265358979f * (float)(1 << (j - 1))))
                        : __cosf(tv * (3.14159265358979f * (float)(1 << (j - 9)))));
    xb[b][64 + j] = f2bf(val);
  }
  __syncthreads();

  // z0 into registers + xb + ztraj step 0
  float zr0, zr1, zr2, zr3;
  {
    const floatx4 zv = *(const floatx4*)&zbuf[r8][fb4];
    zr0 = zv[0]; zr1 = zv[1]; zr2 = zv[2]; zr3 = zv[3];
    if (wv < 4 && rrow < 8) {
      uint2 zp = make_uint2(cvt_pk_bf16(zr0, zr1), cvt_pk_bf16(zr2, zr3));
      *reinterpret_cast<uint2*>(&xb[rrow][fb4]) = zp;
      size_t zi = ((size_t)(blockIdx.x * 8 + rrow) * N_) * 64 + fb4;
      *reinterpret_cast<uint2*>(&ztraj[zi]) = zp;
    }
  }
  __syncthreads();

  // loop-invariant L1 fragments (cols 96-159: static ctx + zero pad)
  short8 xs[2];
  xs[0] = *reinterpret_cast<const short8*>(&xb[r8][96 + g * 8]);
  xs[1] = *reinterpret_cast<const short8*>(&xb[r8][128 + g * 8]);

  for (int n = 0; n < N_ - 1; n++) {
    mlp_layer<5, 3, 8, 168, 168>(wf1, xs, b1, g1, e1, &xb[0][0], &hA[0][0], lnS, wv, lane);
    mlp_layer<4, 4, 8, 168, 168>(wf2, nullptr, b2, g2, e2, &hA[0][0], &hB[0][0], lnS, wv, lane);
    mlp_layer<4, 4, 8, 168, 168>(wf3, nullptr, b3, g3, e3, &hB[0][0], &hA[0][0], lnS, wv, lane);
    if (wv < 4) {
      short8 xf[4];
#pragma unroll
      for (int ks = 0; ks < 4; ks++)
        xf[ks] = *reinterpret_cast<const short8*>(&hA[r8][ks * 32 + g * 8]);
      floatx4 da = b4;
#pragma unroll
      for (int ks = 0; ks < 4; ks++)
        da = __builtin_amdgcn_mfma_f32_16x16x32_bf16(wf4[ks], xf[ks], da, 0, 0, 0);
      float dt = tl[r8][n + 1] - tl[r8][n];
      zr0 += dt * da[0]; zr1 += dt * da[1]; zr2 += dt * da[2]; zr3 += dt * da[3];
      if (rrow < 8) {
        uint2 zp = make_uint2(cvt_pk_bf16(zr0, zr1), cvt_pk_bf16(zr2, zr3));
        *reinterpret_cast<uint2*>(&xb[rrow][fb4]) = zp;
        size_t zi = ((size_t)(blockIdx.x * 8 + rrow) * N_ + (n + 1)) * 64 + fb4;
        *reinterpret_cast<uint2*>(&ztraj[zi]) = zp;
      }
    } else {
      // waves 4-7: next-step Fourier embedding from LDS t, overlapped with L4
      int t2 = tid - 256;
      if (t2 < 136 && n < N_ - 2) {
        int b = t2 / 17, j = t2 - b * 17;
        float tv = tl[b][n + 1];
        float val = (j == 0) ? tv
                  : (j <= 8 ? __sinf(tv * (3.14159265358979f * (float)(1 << (j - 1))))
                            : __cosf(tv * (3.14159265358979f * (float)(1 << (j - 9)))));
        xb[b][64 + j] = f2bf(val);
      }
    }
    __syncthreads();
  }
}

// ---------------- decoder: 512 threads (8 waves), weights in registers, 16 rows/iter,
// grid-stride persistent (2048 WGs); coalesced output flush staged via LDS.
__global__ __launch_bounds__(512, 2) void rlp_dec4(
    const u16* __restrict__ wdec, const u16* __restrict__ ztraj,
    const float* __restrict__ eb0, const float* __restrict__ eb1,
    const float* __restrict__ eb2, const float* __restrict__ eb3,
    const float* __restrict__ eg0, const float* __restrict__ ebe0,
    const float* __restrict__ eg1, const float* __restrict__ ebe1,
    const float* __restrict__ eg2, const float* __restrict__ ebe2,
    float* __restrict__ out, int b0, int nrows) {
  __shared__ __align__(16) u16 xz[16][72];
  __shared__ __align__(16) u16 hA[16][168];
  __shared__ __align__(16) u16 hB[16][168];
  __shared__ __align__(16) float lnD[16 * 20];
  __shared__ float obuf[224];
  __shared__ float bias1[128], bias2[128], bias3[128], bias4[16];
  __shared__ float g1s[128], e1s[128], g2s[128], e2s[128], g3s[128], e3s[128];

  const int tid = threadIdx.x;
  const int wv = tid >> 6;
  const int lane = tid & 63;
  const int rrow = lane & 15;
  const int g = lane >> 4;
  const int fb = 16 * wv + 4 * g;

  short8 wf1[2], wf2[4], wf3[4], wf4[4];
#pragma unroll
  for (int ks = 0; ks < 2; ks++)
    wf1[ks] = *(const short8*)(wdec + ((size_t)(wv * 2 + ks) * 64 + lane) * 8);
#pragma unroll
  for (int ks = 0; ks < 4; ks++)
    wf2[ks] = *(const short8*)(wdec + 8192 + ((size_t)(wv * 4 + ks) * 64 + lane) * 8);
#pragma unroll
  for (int ks = 0; ks < 4; ks++)
    wf3[ks] = *(const short8*)(wdec + 24576 + ((size_t)(wv * 4 + ks) * 64 + lane) * 8);
#pragma unroll
  for (int ks = 0; ks < 4; ks++)
    wf4[ks] = *(const short8*)(wdec + 40960 + ((size_t)ks * 64 + lane) * 8);

  for (int i = tid; i < 128; i += 512) {
    bias1[i] = eb0[i]; bias2[i] = eb1[i]; bias3[i] = eb2[i];
    g1s[i] = eg0[i]; e1s[i] = ebe0[i];
    g2s[i] = eg1[i]; e2s[i] = ebe1[i];
    g3s[i] = eg2[i]; e3s[i] = ebe2[i];
  }
  if (tid < 16) bias4[tid] = (tid < 14) ? eb3[tid] : 0.0f;
  __syncthreads();

  const floatx4 b1 = *(const floatx4*)&bias1[fb];
  const floatx4 g1v = *(const floatx4*)&g1s[fb];
  const floatx4 e1v = *(const floatx4*)&e1s[fb];
  const floatx4 b2 = *(const floatx4*)&bias2[fb];
  const floatx4 g2v = *(const floatx4*)&g2s[fb];
  const floatx4 e2v = *(const floatx4*)&e2s[fb];
  const floatx4 b3 = *(const floatx4*)&bias3[fb];
  const floatx4 g3v = *(const floatx4*)&g3s[fb];
  const floatx4 e3v = *(const floatx4*)&e3s[fb];
  const floatx4 b4 = *(const floatx4*)&bias4[4 * g];

  const int ntiles = nrows >> 4;
  int prevbase = -1;
  for (int tile = blockIdx.x; tile < ntiles; tile += gridDim.x) {
    if (prevbase >= 0 && tid < 224) out[prevbase + tid] = obuf[tid];
    if (tid < 128) {
      int rr = tid >> 3, p = tid & 7;
      *reinterpret_cast<short8*>(&xz[rr][p * 8]) =
          *reinterpret_cast<const short8*>(&ztraj[(size_t)(tile * 16 + rr) * 64 + p * 8]);
    }
    __syncthreads();
    mlp_layer<2, 2, 16, 72, 168>(wf1, nullptr, b1, g1v, e1v, &xz[0][0], &hA[0][0], lnD, wv, lane);
    mlp_layer<4, 4, 16, 168, 168>(wf2, nullptr, b2, g2v, e2v, &hA[0][0], &hB[0][0], lnD, wv, lane);
    mlp_layer<4, 4, 16, 168, 168>(wf3, nullptr, b3, g3v, e3v, &hB[0][0], &hA[0][0], lnD, wv, lane);
    if (wv == 0) {
      short8 xf[4];
#pragma unroll
      for (int ks = 0; ks < 4; ks++)
        xf[ks] = *reinterpret_cast<const short8*>(&hA[rrow][ks * 32 + g * 8]);
      floatx4 da = b4;
#pragma unroll
      for (int ks = 0; ks < 4; ks++)
        da = __builtin_amdgcn_mfma_f32_16x16x32_bf16(wf4[ks], xf[ks], da, 0, 0, 0);
#pragma unroll
      for (int r = 0; r < 4; r++) {
        int wc = 4 * g + r;
        if (wc < 14) obuf[rrow * 14 + wc] = da[r];
      }
    }
    __syncthreads();
    prevbase = b0 * 3584 + tile * 224;
  }
  if (prevbase >= 0 && tid < 224) out[prevbase + tid] = obuf[tid];
}

extern "C" void kernel_launch(void* const* d_in, const int* in_sizes, int n_in,
                              void* d_out, int out_size, void* d_ws, size_t ws_size,
                              hipStream_t stream) {
  const float* t = (const float*)d_in[0];
  const float* ctx = (const float*)d_in[1];
  const float* ce_w = (const float*)d_in[2];
  const float* ce_b = (const float*)d_in[3];
  const float* z0_w = (const float*)d_in[4];
  const float* z0_b = (const float*)d_in[5];
  const float* dw0 = (const float*)d_in[6];
  const float* db0 = (const float*)d_in[7];
  const float* dw1 = (const float*)d_in[8];
  const float* db1 = (const float*)d_in[9];
  const float* dw2 = (const float*)d_in[10];
  const float* db2 = (const float*)d_in[11];
  const float* dw3 = (const float*)d_in[12];
  const float* db3 = (const float*)d_in[13];
  const float* dg0 = (const float*)d_in[14];
  const float* dbe0 = (const float*)d_in[15];
  const float* dg1 = (const float*)d_in[16];
  const float* dbe1 = (const float*)d_in[17];
  const float* dg2 = (const float*)d_in[18];
  const float* dbe2 = (const float*)d_in[19];
  const float* ew0 = (const float*)d_in[20];
  const float* eb0 = (const float*)d_in[21];
  const float* ew1 = (const float*)d_in[22];
  const float* eb1 = (const float*)d_in[23];
  const float* ew2 = (const float*)d_in[24];
  const float* eb2 = (const float*)d_in[25];
  const float* ew3 = (const float*)d_in[26];
  const float* eb3 = (const float*)d_in[27];
  const float* eg0 = (const float*)d_in[28];
  const float* ebe0 = (const float*)d_in[29];
  const float* eg1 = (const float*)d_in[30];
  const float* ebe1 = (const float*)d_in[31];
  const float* eg2 = (const float*)d_in[32];
  const float* ebe2 = (const float*)d_in[33];
  float* out = (float*)d_out;

  char* ws = (char*)d_ws;
  u16* wdyn = (u16*)(ws + 0);            // 61440 elems = 122880 B
  u16* wdec = (u16*)(ws + 122880);       // 43008 elems =  86016 B
  u16* zt = (u16*)(ws + 208896);         // z_traj bf16
  size_t zt_avail = (ws_size > 208896) ? ws_size - 208896 : 0;

  rlp_pack_all<<<408, 256, 0, stream>>>(dw0, dw1, dw2, dw3, ew0, ew1, ew2, ew3, wdyn, wdec);

  const size_t per_row = (size_t)N_ * 64 * 2;
  int chunkB = B_;
  if (zt_avail < (size_t)B_ * per_row) {
    chunkB = (int)(zt_avail / per_row) & ~7;
    if (chunkB < 8) chunkB = 8;
  }
  for (int b0 = 0; b0 < B_; b0 += chunkB) {
    int cb = (B_ - b0 < chunkB) ? (B_ - b0) : chunkB;
    rlp_scan4<<<cb / 8, 512, 0, stream>>>(t, wdyn, ctx, ce_w, ce_b, z0_w, z0_b,
        db0, db1, db2, db3, dg0, dbe0, dg1, dbe1, dg2, dbe2, zt, b0);
    int ntiles = cb * 16;
    int ngrid = ntiles < 2048 ? ntiles : 2048;
    rlp_dec4<<<ngrid, 512, 0, stream>>>(wdec, zt,
        eb0, eb1, eb2, eb3, eg0, ebe0, eg1, ebe1, eg2, ebe2, out, b0, cb * 256);
  }
}

// Round 5
// 916.796 us; speedup vs baseline: 1.8054x; 1.1193x over previous
//
#include <hip/hip_runtime.h>
#include <cstdint>
#include <cstddef>

#define B_ 2048
#define N_ 256

typedef unsigned short u16;
typedef unsigned int u32;
typedef __attribute__((ext_vector_type(8))) short short8;
typedef __attribute__((ext_vector_type(4))) float floatx4;

__device__ __forceinline__ u16 f2bf(float f) {
  union { float f; unsigned u; } v; v.f = f;
  unsigned u = v.u;
  return (u16)((u + 0x7FFFu + ((u >> 16) & 1u)) >> 16);
}
// single-instruction RNE pack of 2 f32 -> 2 bf16 (low=a, high=b)
__device__ __forceinline__ u32 cvt_pk_bf16(float a, float b) {
  u32 r;
  asm("v_cvt_pk_bf16_f32 %0, %1, %2" : "=v"(r) : "v"(a), "v"(b));
  return r;
}
__device__ __forceinline__ float tanh_fast(float x) {
  x = fmaxf(fminf(x, 30.0f), -30.0f);
  float u = __expf(-2.0f * x);
  return __fdividef(1.0f - u, 1.0f + u);
}
// LDS-only barrier: waits ds ops (lgkm) but NOT global stores (vmcnt) — removes the
// per-barrier HBM store-ack drain that __syncthreads() imposes. Cross-thread LDS
// visibility is what the loop needs; compiler still tracks load->use deps itself.
__device__ __forceinline__ void bar_lgkm() {
  asm volatile("s_waitcnt lgkmcnt(0)" ::: "memory");
  __builtin_amdgcn_s_barrier();
  __builtin_amdgcn_sched_barrier(0);
}

// ---------------- combined weight packer (one launch).
// frag order: elem = ((nt*ks + ksi)*64 + lane)*8 + j -> W[ksi*32+(lane>>4)*8+j][nt*16+(lane&15)]
__global__ void rlp_pack_all(const float* __restrict__ dw0, const float* __restrict__ dw1,
                             const float* __restrict__ dw2, const float* __restrict__ dw3,
                             const float* __restrict__ ew0, const float* __restrict__ ew1,
                             const float* __restrict__ ew2, const float* __restrict__ ew3,
                             u16* __restrict__ wdyn, u16* __restrict__ wdec) {
  int e = blockIdx.x * blockDim.x + threadIdx.x;
  const float* W; int K, Nc, ks, base; u16* dst;
  if (e < 20480)       { W = dw0; K = 145; Nc = 128; ks = 5; dst = wdyn;         base = 0; }
  else if (e < 36864)  { W = dw1; K = 128; Nc = 128; ks = 4; dst = wdyn + 20480; base = 20480; }
  else if (e < 53248)  { W = dw2; K = 128; Nc = 128; ks = 4; dst = wdyn + 36864; base = 36864; }
  else if (e < 61440)  { W = dw3; K = 128; Nc = 64;  ks = 4; dst = wdyn + 53248; base = 53248; }
  else if (e < 69632)  { W = ew0; K = 64;  Nc = 128; ks = 2; dst = wdec;         base = 61440; }
  else if (e < 86016)  { W = ew1; K = 128; Nc = 128; ks = 4; dst = wdec + 8192;  base = 69632; }
  else if (e < 102400) { W = ew2; K = 128; Nc = 128; ks = 4; dst = wdec + 24576; base = 86016; }
  else if (e < 104448) { W = ew3; K = 128; Nc = 14;  ks = 4; dst = wdec + 40960; base = 102400; }
  else return;
  int el = e - base;
  int j = el & 7;
  int lane = (el >> 3) & 63;
  int tt = el >> 9;
  int ksi = tt % ks;
  int nt = tt / ks;
  int col = nt * 16 + (lane & 15);
  int k = ksi * 32 + ((lane >> 4) << 3) + j;
  float v = 0.0f;
  if (k < K && col < Nc) v = W[k * Nc + col];
  dst[el] = f2bf(v);
}

// ---------------- one hidden layer (swapped MFMA: A=W frag in VGPR, B=x frag from LDS).
// C[m=wcol][n=brow]: lane&15 = brow, (lane>>4)*4+r = wcol-within-tile.
// KSD dynamic (LDS) k-steps + (KS-KSD) static frags. 2 lgkm-barriers.
template <int KS, int KSD, int NROW, int SSTR, int DSTR>
__device__ __forceinline__ void mlp_layer(
    const short8 (&wf)[KS], const short8* xstat,
    floatx4 bv, floatx4 gv, floatx4 ev,
    const u16* src, u16* dst, float* lnbuf, int wv, int lane) {
  const int rrow = lane & 15;          // batch row (B-col of MFMA)
  const int g = lane >> 4;
  const int srow = (NROW == 8) ? (rrow & 7) : rrow;
  short8 xf[KSD];
#pragma unroll
  for (int ks = 0; ks < KSD; ks++)
    xf[ks] = *reinterpret_cast<const short8*>(&src[srow * SSTR + ks * 32 + g * 8]);
  floatx4 acc = bv;
#pragma unroll
  for (int ks = 0; ks < KSD; ks++)
    acc = __builtin_amdgcn_mfma_f32_16x16x32_bf16(wf[ks], xf[ks], acc, 0, 0, 0);
#pragma unroll
  for (int ks = KSD; ks < KS; ks++)
    acc = __builtin_amdgcn_mfma_f32_16x16x32_bf16(wf[ks], xstat[ks - KSD], acc, 0, 0, 0);
  // per-brow partial sums over this wave's 16 wcols
  float s = acc[0] + acc[1] + acc[2] + acc[3];
  float q = acc[0] * acc[0] + acc[1] * acc[1] + acc[2] * acc[2] + acc[3] * acc[3];
  s += __shfl_xor(s, 16, 64); q += __shfl_xor(q, 16, 64);
  s += __shfl_xor(s, 32, 64); q += __shfl_xor(q, 32, 64);
  if (lane < NROW) {
    *reinterpret_cast<float2*>(&lnbuf[lane * 20 + 2 * wv]) = make_float2(s, q);
  }
  bar_lgkm();
  floatx4 p0 = *reinterpret_cast<const floatx4*>(&lnbuf[srow * 20 + 0]);
  floatx4 p1 = *reinterpret_cast<const floatx4*>(&lnbuf[srow * 20 + 4]);
  floatx4 p2 = *reinterpret_cast<const floatx4*>(&lnbuf[srow * 20 + 8]);
  floatx4 p3 = *reinterpret_cast<const floatx4*>(&lnbuf[srow * 20 + 12]);
  float S = p0[0] + p0[2] + p1[0] + p1[2] + p2[0] + p2[2] + p3[0] + p3[2];
  float Q = p0[1] + p0[3] + p1[1] + p1[3] + p2[1] + p2[3] + p3[1] + p3[3];
  float mean = S * (1.0f / 128.0f);
  float rs = rsqrtf(Q * (1.0f / 128.0f) - mean * mean + 1e-5f);
  float h0 = tanh_fast((acc[0] - mean) * rs * gv[0] + ev[0]);
  float h1 = tanh_fast((acc[1] - mean) * rs * gv[1] + ev[1]);
  float h2 = tanh_fast((acc[2] - mean) * rs * gv[2] + ev[2]);
  float h3 = tanh_fast((acc[3] - mean) * rs * gv[3] + ev[3]);
  if (rrow < NROW) {
    int f = 16 * wv + 4 * g;
    uint2 hp = make_uint2(cvt_pk_bf16(h0, h1), cvt_pk_bf16(h2, h3));
    *reinterpret_cast<uint2*>(&dst[rrow * DSTR + f]) = hp;
  }
  bar_lgkm();
}

// ---------------- scan: 512 threads (8 waves), 8 batch rows per WG, grid 256 (1 WG/CU).
// Weights in registers; t preloaded to LDS; z state in registers of waves 0-3;
// waves 4-7 compute next-step Fourier embedding concurrently with L4.
__global__ __launch_bounds__(512, 1) void rlp_scan5(
    const float* __restrict__ t, const u16* __restrict__ wdyn,
    const float* __restrict__ ctxg, const float* __restrict__ cew,
    const float* __restrict__ ceb, const float* __restrict__ z0w,
    const float* __restrict__ z0b,
    const float* __restrict__ db0, const float* __restrict__ db1,
    const float* __restrict__ db2, const float* __restrict__ db3,
    const float* __restrict__ dg0, const float* __restrict__ dbe0,
    const float* __restrict__ dg1, const float* __restrict__ dbe1,
    const float* __restrict__ dg2, const float* __restrict__ dbe2,
    u16* __restrict__ ztraj, int b0) {
  __shared__ __align__(16) u16 xb[8][168];   // 0-63 z | 64-80 temb | 81-144 ctx | 145-167 zero
  __shared__ __align__(16) u16 hA[8][168];
  __shared__ __align__(16) u16 hB[8][168];
  __shared__ __align__(16) float lnS[8 * 20];
  __shared__ __align__(16) float tl[8][260];
  __shared__ float ctxe[8][64];
  __shared__ float zbuf[8][64];

  const int tid = threadIdx.x;
  const int wv = tid >> 6;
  const int lane = tid & 63;
  const int rrow = lane & 15;
  const int g = lane >> 4;
  const int r8 = rrow & 7;
  const int w4 = wv & 3;
  const int fb = 16 * wv + 4 * g;
  const int fb4 = 16 * w4 + 4 * g;
  const int gb = b0 + blockIdx.x * 8;

  const floatx4 b1 = *(const floatx4*)&db0[fb];
  const floatx4 g1 = *(const floatx4*)&dg0[fb];
  const floatx4 e1 = *(const floatx4*)&dbe0[fb];
  const floatx4 b2 = *(const floatx4*)&db1[fb];
  const floatx4 g2 = *(const floatx4*)&dg1[fb];
  const floatx4 e2 = *(const floatx4*)&dbe1[fb];
  const floatx4 b3 = *(const floatx4*)&db2[fb];
  const floatx4 g3 = *(const floatx4*)&dg2[fb];
  const floatx4 e3 = *(const floatx4*)&dbe2[fb];
  const floatx4 b4 = *(const floatx4*)&db3[fb4];

  short8 wf1[5], wf2[4], wf3[4], wf4[4];
#pragma unroll
  for (int ks = 0; ks < 5; ks++)
    wf1[ks] = *(const short8*)(wdyn + ((size_t)(wv * 5 + ks) * 64 + lane) * 8);
#pragma unroll
  for (int ks = 0; ks < 4; ks++)
    wf2[ks] = *(const short8*)(wdyn + 20480 + ((size_t)(wv * 4 + ks) * 64 + lane) * 8);
#pragma unroll
  for (int ks = 0; ks < 4; ks++)
    wf3[ks] = *(const short8*)(wdyn + 36864 + ((size_t)(wv * 4 + ks) * 64 + lane) * 8);
#pragma unroll
  for (int ks = 0; ks < 4; ks++)
    wf4[ks] = *(const short8*)(wdyn + 53248 + ((size_t)(w4 * 4 + ks) * 64 + lane) * 8);

  // t -> LDS (coalesced) and zero xb
  for (int i = tid; i < 8 * 256; i += 512) {
    int r = i >> 8, c = i & 255;
    tl[r][c] = t[(size_t)(gb + r) * N_ + c];
  }
  for (int i = tid; i < 8 * 168 / 2; i += 512) reinterpret_cast<u32*>(&xb[0][0])[i] = 0;
  __syncthreads();

  // ctx encoder: 8 rows x 64 cols over all 512 threads
  {
    int b = tid >> 6, c = tid & 63;
    float s = ceb[c];
#pragma unroll
    for (int k = 0; k < 32; k++) s += ctxg[(size_t)(gb + b) * 32 + k] * cew[k * 64 + c];
    float v = tanh_fast(s);
    ctxe[b][c] = v;
    xb[b][81 + c] = f2bf(v);
  }
  __syncthreads();
  // z0 encoder
  {
    int b = tid >> 6, l = tid & 63;
    float s = z0b[l];
#pragma unroll 8
    for (int k = 0; k < 64; k++) s += ctxe[b][k] * z0w[k * 64 + l];
    zbuf[b][l] = tanh_fast(s);
  }
  // temb(0)
  if (tid < 136) {
    int b = tid / 17, j = tid - b * 17;
    float tv = tl[b][0];
    float val = (j == 0) ? tv
              : (j <= 8 ? __sinf(tv * (3.14159265358979f * (float)(1 << (j - 1))))
                        : __cosf(tv * (3.14159265358979f * (float)(1 << (j - 9)))));
    xb[b][64 + j] = f2bf(val);
  }
  __syncthreads();

  // z0 into registers + xb + ztraj step 0
  float zr0, zr1, zr2, zr3;
  {
    const floatx4 zv = *(const floatx4*)&zbuf[r8][fb4];
    zr0 = zv[0]; zr1 = zv[1]; zr2 = zv[2]; zr3 = zv[3];
    if (wv < 4 && rrow < 8) {
      uint2 zp = make_uint2(cvt_pk_bf16(zr0, zr1), cvt_pk_bf16(zr2, zr3));
      *reinterpret_cast<uint2*>(&xb[rrow][fb4]) = zp;
      size_t zi = ((size_t)(blockIdx.x * 8 + rrow) * N_) * 64 + fb4;
      *reinterpret_cast<uint2*>(&ztraj[zi]) = zp;
    }
  }
  __syncthreads();

  // loop-invariant L1 fragments (cols 96-159: static ctx + zero pad)
  short8 xs[2];
  xs[0] = *reinterpret_cast<const short8*>(&xb[r8][96 + g * 8]);
  xs[1] = *reinterpret_cast<const short8*>(&xb[r8][128 + g * 8]);

  for (int n = 0; n < N_ - 1; n++) {
    mlp_layer<5, 3, 8, 168, 168>(wf1, xs, b1, g1, e1, &xb[0][0], &hA[0][0], lnS, wv, lane);
    mlp_layer<4, 4, 8, 168, 168>(wf2, nullptr, b2, g2, e2, &hA[0][0], &hB[0][0], lnS, wv, lane);
    mlp_layer<4, 4, 8, 168, 168>(wf3, nullptr, b3, g3, e3, &hB[0][0], &hA[0][0], lnS, wv, lane);
    if (wv < 4) {
      short8 xf[4];
#pragma unroll
      for (int ks = 0; ks < 4; ks++)
        xf[ks] = *reinterpret_cast<const short8*>(&hA[r8][ks * 32 + g * 8]);
      floatx4 da = b4;
#pragma unroll
      for (int ks = 0; ks < 4; ks++)
        da = __builtin_amdgcn_mfma_f32_16x16x32_bf16(wf4[ks], xf[ks], da, 0, 0, 0);
      float dt = tl[r8][n + 1] - tl[r8][n];
      zr0 += dt * da[0]; zr1 += dt * da[1]; zr2 += dt * da[2]; zr3 += dt * da[3];
      if (rrow < 8) {
        uint2 zp = make_uint2(cvt_pk_bf16(zr0, zr1), cvt_pk_bf16(zr2, zr3));
        *reinterpret_cast<uint2*>(&xb[rrow][fb4]) = zp;
        size_t zi = ((size_t)(blockIdx.x * 8 + rrow) * N_ + (n + 1)) * 64 + fb4;
        *reinterpret_cast<uint2*>(&ztraj[zi]) = zp;
      }
    } else {
      // waves 4-7: next-step Fourier embedding from LDS t, overlapped with L4
      int t2 = tid - 256;
      if (t2 < 136 && n < N_ - 2) {
        int b = t2 / 17, j = t2 - b * 17;
        float tv = tl[b][n + 1];
        float val = (j == 0) ? tv
                  : (j <= 8 ? __sinf(tv * (3.14159265358979f * (float)(1 << (j - 1))))
                            : __cosf(tv * (3.14159265358979f * (float)(1 << (j - 9)))));
        xb[b][64 + j] = f2bf(val);
      }
    }
    bar_lgkm();
  }
}

// ---------------- decoder: 512 threads (8 waves), weights in registers, 16 rows/iter,
// grid-stride persistent, 4 blocks/CU (TLP); coalesced output flush staged via LDS.
__global__ __launch_bounds__(512, 4) void rlp_dec5(
    const u16* __restrict__ wdec, const u16* __restrict__ ztraj,
    const float* __restrict__ eb0, const float* __restrict__ eb1,
    const float* __restrict__ eb2, const float* __restrict__ eb3,
    const float* __restrict__ eg0, const float* __restrict__ ebe0,
    const float* __restrict__ eg1, const float* __restrict__ ebe1,
    const float* __restrict__ eg2, const float* __restrict__ ebe2,
    float* __restrict__ out, int b0, int nrows) {
  __shared__ __align__(16) u16 xz[16][72];
  __shared__ __align__(16) u16 hA[16][168];
  __shared__ __align__(16) u16 hB[16][168];
  __shared__ __align__(16) float lnD[16 * 20];
  __shared__ float obuf[224];
  __shared__ float bias1[128], bias2[128], bias3[128], bias4[16];
  __shared__ float g1s[128], e1s[128], g2s[128], e2s[128], g3s[128], e3s[128];

  const int tid = threadIdx.x;
  const int wv = tid >> 6;
  const int lane = tid & 63;
  const int rrow = lane & 15;
  const int g = lane >> 4;
  const int fb = 16 * wv + 4 * g;

  short8 wf1[2], wf2[4], wf3[4], wf4[4];
#pragma unroll
  for (int ks = 0; ks < 2; ks++)
    wf1[ks] = *(const short8*)(wdec + ((size_t)(wv * 2 + ks) * 64 + lane) * 8);
#pragma unroll
  for (int ks = 0; ks < 4; ks++)
    wf2[ks] = *(const short8*)(wdec + 8192 + ((size_t)(wv * 4 + ks) * 64 + lane) * 8);
#pragma unroll
  for (int ks = 0; ks < 4; ks++)
    wf3[ks] = *(const short8*)(wdec + 24576 + ((size_t)(wv * 4 + ks) * 64 + lane) * 8);
#pragma unroll
  for (int ks = 0; ks < 4; ks++)
    wf4[ks] = *(const short8*)(wdec + 40960 + ((size_t)ks * 64 + lane) * 8);

  for (int i = tid; i < 128; i += 512) {
    bias1[i] = eb0[i]; bias2[i] = eb1[i]; bias3[i] = eb2[i];
    g1s[i] = eg0[i]; e1s[i] = ebe0[i];
    g2s[i] = eg1[i]; e2s[i] = ebe1[i];
    g3s[i] = eg2[i]; e3s[i] = ebe2[i];
  }
  if (tid < 16) bias4[tid] = (tid < 14) ? eb3[tid] : 0.0f;
  __syncthreads();

  const floatx4 b1 = *(const floatx4*)&bias1[fb];
  const floatx4 g1v = *(const floatx4*)&g1s[fb];
  const floatx4 e1v = *(const floatx4*)&e1s[fb];
  const floatx4 b2 = *(const floatx4*)&bias2[fb];
  const floatx4 g2v = *(const floatx4*)&g2s[fb];
  const floatx4 e2v = *(const floatx4*)&e2s[fb];
  const floatx4 b3 = *(const floatx4*)&bias3[fb];
  const floatx4 g3v = *(const floatx4*)&g3s[fb];
  const floatx4 e3v = *(const floatx4*)&e3s[fb];
  const floatx4 b4 = *(const floatx4*)&bias4[4 * g];

  const int ntiles = nrows >> 4;
  int prevbase = -1;
  for (int tile = blockIdx.x; tile < ntiles; tile += gridDim.x) {
    if (prevbase >= 0 && tid < 224) out[prevbase + tid] = obuf[tid];
    if (tid < 128) {
      int rr = tid >> 3, p = tid & 7;
      *reinterpret_cast<short8*>(&xz[rr][p * 8]) =
          *reinterpret_cast<const short8*>(&ztraj[(size_t)(tile * 16 + rr) * 64 + p * 8]);
    }
    bar_lgkm();
    mlp_layer<2, 2, 16, 72, 168>(wf1, nullptr, b1, g1v, e1v, &xz[0][0], &hA[0][0], lnD, wv, lane);
    mlp_layer<4, 4, 16, 168, 168>(wf2, nullptr, b2, g2v, e2v, &hA[0][0], &hB[0][0], lnD, wv, lane);
    mlp_layer<4, 4, 16, 168, 168>(wf3, nullptr, b3, g3v, e3v, &hB[0][0], &hA[0][0], lnD, wv, lane);
    if (wv == 0) {
      short8 xf[4];
#pragma unroll
      for (int ks = 0; ks < 4; ks++)
        xf[ks] = *reinterpret_cast<const short8*>(&hA[rrow][ks * 32 + g * 8]);
      floatx4 da = b4;
#pragma unroll
      for (int ks = 0; ks < 4; ks++)
        da = __builtin_amdgcn_mfma_f32_16x16x32_bf16(wf4[ks], xf[ks], da, 0, 0, 0);
#pragma unroll
      for (int r = 0; r < 4; r++) {
        int wc = 4 * g + r;
        if (wc < 14) obuf[rrow * 14 + wc] = da[r];
      }
    }
    bar_lgkm();
    prevbase = b0 * 3584 + tile * 224;
  }
  if (prevbase >= 0 && tid < 224) out[prevbase + tid] = obuf[tid];
}

extern "C" void kernel_launch(void* const* d_in, const int* in_sizes, int n_in,
                              void* d_out, int out_size, void* d_ws, size_t ws_size,
                              hipStream_t stream) {
  const float* t = (const float*)d_in[0];
  const float* ctx = (const float*)d_in[1];
  const float* ce_w = (const float*)d_in[2];
  const float* ce_b = (const float*)d_in[3];
  const float* z0_w = (const float*)d_in[4];
  const float* z0_b = (const float*)d_in[5];
  const float* dw0 = (const float*)d_in[6];
  const float* db0 = (const float*)d_in[7];
  const float* dw1 = (const float*)d_in[8];
  const float* db1 = (const float*)d_in[9];
  const float* dw2 = (const float*)d_in[10];
  const float* db2 = (const float*)d_in[11];
  const float* dw3 = (const float*)d_in[12];
  const float* db3 = (const float*)d_in[13];
  const float* dg0 = (const float*)d_in[14];
  const float* dbe0 = (const float*)d_in[15];
  const float* dg1 = (const float*)d_in[16];
  const float* dbe1 = (const float*)d_in[17];
  const float* dg2 = (const float*)d_in[18];
  const float* dbe2 = (const float*)d_in[19];
  const float* ew0 = (const float*)d_in[20];
  const float* eb0 = (const float*)d_in[21];
  const float* ew1 = (const float*)d_in[22];
  const float* eb1 = (const float*)d_in[23];
  const float* ew2 = (const float*)d_in[24];
  const float* eb2 = (const float*)d_in[25];
  const float* ew3 = (const float*)d_in[26];
  const float* eb3 = (const float*)d_in[27];
  const float* eg0 = (const float*)d_in[28];
  const float* ebe0 = (const float*)d_in[29];
  const float* eg1 = (const float*)d_in[30];
  const float* ebe1 = (const float*)d_in[31];
  const float* eg2 = (const float*)d_in[32];
  const float* ebe2 = (const float*)d_in[33];
  float* out = (float*)d_out;

  char* ws = (char*)d_ws;
  u16* wdyn = (u16*)(ws + 0);            // 61440 elems = 122880 B
  u16* wdec = (u16*)(ws + 122880);       // 43008 elems =  86016 B
  u16* zt = (u16*)(ws + 208896);         // z_traj bf16
  size_t zt_avail = (ws_size > 208896) ? ws_size - 208896 : 0;

  rlp_pack_all<<<408, 256, 0, stream>>>(dw0, dw1, dw2, dw3, ew0, ew1, ew2, ew3, wdyn, wdec);

  const size_t per_row = (size_t)N_ * 64 * 2;
  int chunkB = B_;
  if (zt_avail < (size_t)B_ * per_row) {
    chunkB = (int)(zt_avail / per_row) & ~7;
    if (chunkB < 8) chunkB = 8;
  }
  for (int b0 = 0; b0 < B_; b0 += chunkB) {
    int cb = (B_ - b0 < chunkB) ? (B_ - b0) : chunkB;
    rlp_scan5<<<cb / 8, 512, 0, stream>>>(t, wdyn, ctx, ce_w, ce_b, z0_w, z0_b,
        db0, db1, db2, db3, dg0, dbe0, dg1, dbe1, dg2, dbe2, zt, b0);
    int ntiles = cb * 16;
    int ngrid = ntiles < 1024 ? ntiles : 1024;
    rlp_dec5<<<ngrid, 512, 0, stream>>>(wdec, zt,
        eb0, eb1, eb2, eb3, eg0, ebe0, eg1, ebe1, eg2, ebe2, out, b0, cb * 256);
  }
}

// Round 7
// 695.259 us; speedup vs baseline: 2.3807x; 1.3186x over previous
//
#include <hip/hip_runtime.h>
#include <cstdint>
#include <cstddef>

#define B_ 2048
#define N_ 256

typedef unsigned short u16;
typedef unsigned int u32;
typedef __attribute__((ext_vector_type(8))) short short8;
typedef __attribute__((ext_vector_type(4))) float floatx4;

__device__ __forceinline__ u16 f2bf(float f) {
  union { float f; unsigned u; } v; v.f = f;
  unsigned u = v.u;
  return (u16)((u + 0x7FFFu + ((u >> 16) & 1u)) >> 16);
}
__device__ __forceinline__ u32 cvt_pk_bf16(float a, float b) {
  u32 r;
  asm("v_cvt_pk_bf16_f32 %0, %1, %2" : "=v"(r) : "v"(a), "v"(b));
  return r;
}
#define CC_ 2.885390081777927f  /* 2*log2(e) */
// tanh(x) = 1 - 2/(1 + exp2(x*2log2e)) ; 4 VALU ops, no clamp needed
__device__ __forceinline__ float tanh_fast(float x) {
  float u = __builtin_amdgcn_exp2f(x * CC_);
  return fmaf(__builtin_amdgcn_rcpf(u + 1.0f), -2.0f, 1.0f);
}
// Fourier: sin(pi*t*2^(jj-1)) = v_sin(fract(t*2^(jj-2))) (v_sin takes revolutions; exact pow2 scale)
__device__ __forceinline__ float four_emb(float tv, int j) {
  if (j == 0) return tv;
  int jj = (j <= 8) ? j : j - 8;
  float sc = __int_as_float((jj + 125) << 23);  // 2^(jj-2)
  float r = __builtin_amdgcn_fractf(tv * sc);
  return (j <= 8) ? __builtin_amdgcn_sinf(r) : __builtin_amdgcn_cosf(r);
}
// LDS-only barrier (no vmcnt drain)
__device__ __forceinline__ void bar_lgkm() {
  asm volatile("s_waitcnt lgkmcnt(0)" ::: "memory");
  __builtin_amdgcn_s_barrier();
  __builtin_amdgcn_sched_barrier(0);
}

// ---------------- combined weight packer (one launch).
__global__ void rlp_pack_all(const float* __restrict__ dw0, const float* __restrict__ dw1,
                             const float* __restrict__ dw2, const float* __restrict__ dw3,
                             const float* __restrict__ ew0, const float* __restrict__ ew1,
                             const float* __restrict__ ew2, const float* __restrict__ ew3,
                             u16* __restrict__ wdyn, u16* __restrict__ wdec) {
  int e = blockIdx.x * blockDim.x + threadIdx.x;
  const float* W; int K, Nc, ks, base; u16* dst;
  if (e < 20480)       { W = dw0; K = 145; Nc = 128; ks = 5; dst = wdyn;         base = 0; }
  else if (e < 36864)  { W = dw1; K = 128; Nc = 128; ks = 4; dst = wdyn + 20480; base = 20480; }
  else if (e < 53248)  { W = dw2; K = 128; Nc = 128; ks = 4; dst = wdyn + 36864; base = 36864; }
  else if (e < 61440)  { W = dw3; K = 128; Nc = 64;  ks = 4; dst = wdyn + 53248; base = 53248; }
  else if (e < 69632)  { W = ew0; K = 64;  Nc = 128; ks = 2; dst = wdec;         base = 61440; }
  else if (e < 86016)  { W = ew1; K = 128; Nc = 128; ks = 4; dst = wdec + 8192;  base = 69632; }
  else if (e < 102400) { W = ew2; K = 128; Nc = 128; ks = 4; dst = wdec + 24576; base = 86016; }
  else if (e < 104448) { W = ew3; K = 128; Nc = 14;  ks = 4; dst = wdec + 40960; base = 102400; }
  else return;
  int el = e - base;
  int j = el & 7;
  int lane = (el >> 3) & 63;
  int tt = el >> 9;
  int ksi = tt % ks;
  int nt = tt / ks;
  int col = nt * 16 + (lane & 15);
  int k = ksi * 32 + ((lane >> 4) << 3) + j;
  float v = 0.0f;
  if (k < K && col < Nc) v = W[k * Nc + col];
  dst[el] = f2bf(v);
}

// ---------------- one hidden layer. Av = g*2log2e, Ev = beta*2log2e (folded loop-invariantly).
// Swapped MFMA: A=W frag in VGPR, B=x frag from LDS; C[wcol][brow].
// Cross-lane LN partials via __shfl_xor (proven); 2 lgkm-barriers.
template <int KS, int KSD, int NROW, int SSTR, int DSTR>
__device__ __forceinline__ void mlp_layer(
    const short8 (&wf)[KS], const short8* xstat, floatx4 bv,
    floatx4 Av, floatx4 Ev,
    const u16* src, u16* dst, float* lnbuf, int wv, int lane) {
  const int rrow = lane & 15;
  const int g = lane >> 4;
  const int srow = (NROW == 8) ? (rrow & 7) : rrow;
  short8 xf[KSD];
#pragma unroll
  for (int ks = 0; ks < KSD; ks++)
    xf[ks] = *reinterpret_cast<const short8*>(&src[srow * SSTR + ks * 32 + g * 8]);
  floatx4 acc = bv;
#pragma unroll
  for (int ks = 0; ks < KSD; ks++)
    acc = __builtin_amdgcn_mfma_f32_16x16x32_bf16(wf[ks], xf[ks], acc, 0, 0, 0);
#pragma unroll
  for (int ks = KSD; ks < KS; ks++)
    acc = __builtin_amdgcn_mfma_f32_16x16x32_bf16(wf[ks], xstat[ks - KSD], acc, 0, 0, 0);
  float s = acc[0] + acc[1] + acc[2] + acc[3];
  float q = acc[0] * acc[0] + acc[1] * acc[1] + acc[2] * acc[2] + acc[3] * acc[3];
  s += __shfl_xor(s, 16, 64); q += __shfl_xor(q, 16, 64);
  s += __shfl_xor(s, 32, 64); q += __shfl_xor(q, 32, 64);
  if (lane < NROW)
    *reinterpret_cast<float2*>(&lnbuf[lane * 20 + 2 * wv]) = make_float2(s, q);
  bar_lgkm();
  floatx4 p0 = *reinterpret_cast<const floatx4*>(&lnbuf[srow * 20 + 0]);
  floatx4 p1 = *reinterpret_cast<const floatx4*>(&lnbuf[srow * 20 + 4]);
  floatx4 p2 = *reinterpret_cast<const floatx4*>(&lnbuf[srow * 20 + 8]);
  floatx4 p3 = *reinterpret_cast<const floatx4*>(&lnbuf[srow * 20 + 12]);
  float S = p0[0] + p0[2] + p1[0] + p1[2] + p2[0] + p2[2] + p3[0] + p3[2];
  float Q = p0[1] + p0[3] + p1[1] + p1[3] + p2[1] + p2[3] + p3[1] + p3[3];
  float mean = S * 0.0078125f;
  float var = fmaf(Q, 0.0078125f, -mean * mean);
  float rs = __builtin_amdgcn_rsqf(var + 1e-5f);
  // arg = ((acc-mean)*rs*g + be)*2log2e ; tanh = 1 - 2/(1+exp2(arg))
  float a0 = fmaf((acc[0] - mean) * rs, Av[0], Ev[0]);
  float a1 = fmaf((acc[1] - mean) * rs, Av[1], Ev[1]);
  float a2 = fmaf((acc[2] - mean) * rs, Av[2], Ev[2]);
  float a3 = fmaf((acc[3] - mean) * rs, Av[3], Ev[3]);
  float h0 = fmaf(__builtin_amdgcn_rcpf(__builtin_amdgcn_exp2f(a0) + 1.0f), -2.0f, 1.0f);
  float h1 = fmaf(__builtin_amdgcn_rcpf(__builtin_amdgcn_exp2f(a1) + 1.0f), -2.0f, 1.0f);
  float h2 = fmaf(__builtin_amdgcn_rcpf(__builtin_amdgcn_exp2f(a2) + 1.0f), -2.0f, 1.0f);
  float h3 = fmaf(__builtin_amdgcn_rcpf(__builtin_amdgcn_exp2f(a3) + 1.0f), -2.0f, 1.0f);
  if (rrow < NROW) {
    int f = 16 * wv + 4 * g;
    uint2 hp = make_uint2(cvt_pk_bf16(h0, h1), cvt_pk_bf16(h2, h3));
    *reinterpret_cast<uint2*>(&dst[rrow * DSTR + f]) = hp;
  }
  bar_lgkm();
}

// ---------------- scan: 512 threads (8 waves), 8 rows/WG, grid 256.
__global__ __launch_bounds__(512, 1) void rlp_scan7(
    const float* __restrict__ t, const u16* __restrict__ wdyn,
    const float* __restrict__ ctxg, const float* __restrict__ cew,
    const float* __restrict__ ceb, const float* __restrict__ z0w,
    const float* __restrict__ z0b,
    const float* __restrict__ db0, const float* __restrict__ db1,
    const float* __restrict__ db2, const float* __restrict__ db3,
    const float* __restrict__ dg0, const float* __restrict__ dbe0,
    const float* __restrict__ dg1, const float* __restrict__ dbe1,
    const float* __restrict__ dg2, const float* __restrict__ dbe2,
    u16* __restrict__ ztraj, int b0) {
  __shared__ __align__(16) u16 xb[8][168];
  __shared__ __align__(16) u16 hA[8][168];
  __shared__ __align__(16) u16 hB[8][168];
  __shared__ __align__(16) float lnS[8 * 20];
  __shared__ __align__(16) float tl[8][260];
  __shared__ float ctxe[8][64];
  __shared__ float zbuf[8][64];

  const int tid = threadIdx.x;
  const int wv = tid >> 6;
  const int lane = tid & 63;
  const int rrow = lane & 15;
  const int g = lane >> 4;
  const int r8 = rrow & 7;
  const int w4 = wv & 3;
  const int fb = 16 * wv + 4 * g;
  const int fb4 = 16 * w4 + 4 * g;
  const int gb = b0 + blockIdx.x * 8;

  const floatx4 b1 = *(const floatx4*)&db0[fb];
  const floatx4 g1v = *(const floatx4*)&dg0[fb];
  const floatx4 e1v = *(const floatx4*)&dbe0[fb];
  const floatx4 b2 = *(const floatx4*)&db1[fb];
  const floatx4 g2v = *(const floatx4*)&dg1[fb];
  const floatx4 e2v = *(const floatx4*)&dbe1[fb];
  const floatx4 b3 = *(const floatx4*)&db2[fb];
  const floatx4 g3v = *(const floatx4*)&dg2[fb];
  const floatx4 e3v = *(const floatx4*)&dbe2[fb];
  const floatx4 b4 = *(const floatx4*)&db3[fb4];
  const floatx4 A1 = {g1v[0] * CC_, g1v[1] * CC_, g1v[2] * CC_, g1v[3] * CC_};
  const floatx4 E1 = {e1v[0] * CC_, e1v[1] * CC_, e1v[2] * CC_, e1v[3] * CC_};
  const floatx4 A2 = {g2v[0] * CC_, g2v[1] * CC_, g2v[2] * CC_, g2v[3] * CC_};
  const floatx4 E2 = {e2v[0] * CC_, e2v[1] * CC_, e2v[2] * CC_, e2v[3] * CC_};
  const floatx4 A3 = {g3v[0] * CC_, g3v[1] * CC_, g3v[2] * CC_, g3v[3] * CC_};
  const floatx4 E3 = {e3v[0] * CC_, e3v[1] * CC_, e3v[2] * CC_, e3v[3] * CC_};

  short8 wf1[5], wf2[4], wf3[4], wf4[4];
#pragma unroll
  for (int ks = 0; ks < 5; ks++)
    wf1[ks] = *(const short8*)(wdyn + ((size_t)(wv * 5 + ks) * 64 + lane) * 8);
#pragma unroll
  for (int ks = 0; ks < 4; ks++)
    wf2[ks] = *(const short8*)(wdyn + 20480 + ((size_t)(wv * 4 + ks) * 64 + lane) * 8);
#pragma unroll
  for (int ks = 0; ks < 4; ks++)
    wf3[ks] = *(const short8*)(wdyn + 36864 + ((size_t)(wv * 4 + ks) * 64 + lane) * 8);
#pragma unroll
  for (int ks = 0; ks < 4; ks++)
    wf4[ks] = *(const short8*)(wdyn + 53248 + ((size_t)(w4 * 4 + ks) * 64 + lane) * 8);

  for (int i = tid; i < 8 * 256; i += 512) {
    int r = i >> 8, c = i & 255;
    tl[r][c] = t[(size_t)(gb + r) * N_ + c];
  }
  for (int i = tid; i < 8 * 168 / 2; i += 512) reinterpret_cast<u32*>(&xb[0][0])[i] = 0;
  __syncthreads();

  {
    int b = tid >> 6, c = tid & 63;
    float s = ceb[c];
#pragma unroll
    for (int k = 0; k < 32; k++) s += ctxg[(size_t)(gb + b) * 32 + k] * cew[k * 64 + c];
    float v = tanh_fast(s);
    ctxe[b][c] = v;
    xb[b][81 + c] = f2bf(v);
  }
  __syncthreads();
  {
    int b = tid >> 6, l = tid & 63;
    float s = z0b[l];
#pragma unroll 8
    for (int k = 0; k < 64; k++) s += ctxe[b][k] * z0w[k * 64 + l];
    zbuf[b][l] = tanh_fast(s);
  }
  if (tid < 136) {
    int b = tid / 17, j = tid - b * 17;
    xb[b][64 + j] = f2bf(four_emb(tl[b][0], j));
  }
  __syncthreads();

  float zr0, zr1, zr2, zr3;
  {
    const floatx4 zv = *(const floatx4*)&zbuf[r8][fb4];
    zr0 = zv[0]; zr1 = zv[1]; zr2 = zv[2]; zr3 = zv[3];
    if (wv < 4 && rrow < 8) {
      uint2 zp = make_uint2(cvt_pk_bf16(zr0, zr1), cvt_pk_bf16(zr2, zr3));
      *reinterpret_cast<uint2*>(&xb[rrow][fb4]) = zp;
      size_t zi = ((size_t)(blockIdx.x * 8 + rrow) * N_) * 64 + fb4;
      *reinterpret_cast<uint2*>(&ztraj[zi]) = zp;
    }
  }
  __syncthreads();

  short8 xs[2];
  xs[0] = *reinterpret_cast<const short8*>(&xb[r8][96 + g * 8]);
  xs[1] = *reinterpret_cast<const short8*>(&xb[r8][128 + g * 8]);

  for (int n = 0; n < N_ - 1; n++) {
    mlp_layer<5, 3, 8, 168, 168>(wf1, xs, b1, A1, E1, &xb[0][0], &hA[0][0], lnS, wv, lane);
    mlp_layer<4, 4, 8, 168, 168>(wf2, nullptr, b2, A2, E2, &hA[0][0], &hB[0][0], lnS, wv, lane);
    mlp_layer<4, 4, 8, 168, 168>(wf3, nullptr, b3, A3, E3, &hB[0][0], &hA[0][0], lnS, wv, lane);
    if (wv < 4) {
      short8 xf[4];
#pragma unroll
      for (int ks = 0; ks < 4; ks++)
        xf[ks] = *reinterpret_cast<const short8*>(&hA[r8][ks * 32 + g * 8]);
      floatx4 da = b4;
#pragma unroll
      for (int ks = 0; ks < 4; ks++)
        da = __builtin_amdgcn_mfma_f32_16x16x32_bf16(wf4[ks], xf[ks], da, 0, 0, 0);
      float dt = tl[r8][n + 1] - tl[r8][n];
      zr0 += dt * da[0]; zr1 += dt * da[1]; zr2 += dt * da[2]; zr3 += dt * da[3];
      if (rrow < 8) {
        uint2 zp = make_uint2(cvt_pk_bf16(zr0, zr1), cvt_pk_bf16(zr2, zr3));
        *reinterpret_cast<uint2*>(&xb[rrow][fb4]) = zp;
        size_t zi = ((size_t)(blockIdx.x * 8 + rrow) * N_ + (n + 1)) * 64 + fb4;
        *reinterpret_cast<uint2*>(&ztraj[zi]) = zp;
      }
    } else {
      int t2 = tid - 256;
      if (t2 < 136 && n < N_ - 2) {
        int b = t2 / 17, j = t2 - b * 17;
        xb[b][64 + j] = f2bf(four_emb(tl[b][n + 1], j));
      }
    }
    bar_lgkm();
  }
}

// ---------------- decoder: 512 threads, 4 blocks/CU, 16 rows/iter, grid-stride.
__global__ __launch_bounds__(512, 4) void rlp_dec7(
    const u16* __restrict__ wdec, const u16* __restrict__ ztraj,
    const float* __restrict__ eb0, const float* __restrict__ eb1,
    const float* __restrict__ eb2, const float* __restrict__ eb3,
    const float* __restrict__ eg0, const float* __restrict__ ebe0,
    const float* __restrict__ eg1, const float* __restrict__ ebe1,
    const float* __restrict__ eg2, const float* __restrict__ ebe2,
    float* __restrict__ out, int b0, int nrows) {
  __shared__ __align__(16) u16 xz[16][72];
  __shared__ __align__(16) u16 hA[16][168];
  __shared__ __align__(16) u16 hB[16][168];
  __shared__ __align__(16) float lnD[16 * 20];
  __shared__ float obuf[224];
  __shared__ float bias1[128], bias2[128], bias3[128], bias4[16];
  __shared__ float g1s[128], e1s[128], g2s[128], e2s[128], g3s[128], e3s[128];

  const int tid = threadIdx.x;
  const int wv = tid >> 6;
  const int lane = tid & 63;
  const int rrow = lane & 15;
  const int g = lane >> 4;
  const int fb = 16 * wv + 4 * g;

  short8 wf1[2], wf2[4], wf3[4], wf4[4];
#pragma unroll
  for (int ks = 0; ks < 2; ks++)
    wf1[ks] = *(const short8*)(wdec + ((size_t)(wv * 2 + ks) * 64 + lane) * 8);
#pragma unroll
  for (int ks = 0; ks < 4; ks++)
    wf2[ks] = *(const short8*)(wdec + 8192 + ((size_t)(wv * 4 + ks) * 64 + lane) * 8);
#pragma unroll
  for (int ks = 0; ks < 4; ks++)
    wf3[ks] = *(const short8*)(wdec + 24576 + ((size_t)(wv * 4 + ks) * 64 + lane) * 8);
#pragma unroll
  for (int ks = 0; ks < 4; ks++)
    wf4[ks] = *(const short8*)(wdec + 40960 + ((size_t)ks * 64 + lane) * 8);

  for (int i = tid; i < 128; i += 512) {
    bias1[i] = eb0[i]; bias2[i] = eb1[i]; bias3[i] = eb2[i];
    g1s[i] = eg0[i]; e1s[i] = ebe0[i];
    g2s[i] = eg1[i]; e2s[i] = ebe1[i];
    g3s[i] = eg2[i]; e3s[i] = ebe2[i];
  }
  if (tid < 16) bias4[tid] = (tid < 14) ? eb3[tid] : 0.0f;
  __syncthreads();

  const floatx4 b1 = *(const floatx4*)&bias1[fb];
  const floatx4 g1v = *(const floatx4*)&g1s[fb];
  const floatx4 e1v = *(const floatx4*)&e1s[fb];
  const floatx4 b2 = *(const floatx4*)&bias2[fb];
  const floatx4 g2v = *(const floatx4*)&g2s[fb];
  const floatx4 e2v = *(const floatx4*)&e2s[fb];
  const floatx4 b3 = *(const floatx4*)&bias3[fb];
  const floatx4 g3v = *(const floatx4*)&g3s[fb];
  const floatx4 e3v = *(const floatx4*)&e3s[fb];
  const floatx4 b4 = *(const floatx4*)&bias4[4 * g];
  const floatx4 A1 = {g1v[0] * CC_, g1v[1] * CC_, g1v[2] * CC_, g1v[3] * CC_};
  const floatx4 E1 = {e1v[0] * CC_, e1v[1] * CC_, e1v[2] * CC_, e1v[3] * CC_};
  const floatx4 A2 = {g2v[0] * CC_, g2v[1] * CC_, g2v[2] * CC_, g2v[3] * CC_};
  const floatx4 E2 = {e2v[0] * CC_, e2v[1] * CC_, e2v[2] * CC_, e2v[3] * CC_};
  const floatx4 A3 = {g3v[0] * CC_, g3v[1] * CC_, g3v[2] * CC_, g3v[3] * CC_};
  const floatx4 E3 = {e3v[0] * CC_, e3v[1] * CC_, e3v[2] * CC_, e3v[3] * CC_};

  const int ntiles = nrows >> 4;
  int prevbase = -1;
  for (int tile = blockIdx.x; tile < ntiles; tile += gridDim.x) {
    if (prevbase >= 0 && tid < 224) out[prevbase + tid] = obuf[tid];
    if (tid < 128) {
      int rr = tid >> 3, p = tid & 7;
      *reinterpret_cast<short8*>(&xz[rr][p * 8]) =
          *reinterpret_cast<const short8*>(&ztraj[(size_t)(tile * 16 + rr) * 64 + p * 8]);
    }
    bar_lgkm();
    mlp_layer<2, 2, 16, 72, 168>(wf1, nullptr, b1, A1, E1, &xz[0][0], &hA[0][0], lnD, wv, lane);
    mlp_layer<4, 4, 16, 168, 168>(wf2, nullptr, b2, A2, E2, &hA[0][0], &hB[0][0], lnD, wv, lane);
    mlp_layer<4, 4, 16, 168, 168>(wf3, nullptr, b3, A3, E3, &hB[0][0], &hA[0][0], lnD, wv, lane);
    if (wv == 0) {
      short8 xf[4];
#pragma unroll
      for (int ks = 0; ks < 4; ks++)
        xf[ks] = *reinterpret_cast<const short8*>(&hA[rrow][ks * 32 + g * 8]);
      floatx4 da = b4;
#pragma unroll
      for (int ks = 0; ks < 4; ks++)
        da = __builtin_amdgcn_mfma_f32_16x16x32_bf16(wf4[ks], xf[ks], da, 0, 0, 0);
#pragma unroll
      for (int r = 0; r < 4; r++) {
        int wc = 4 * g + r;
        if (wc < 14) obuf[rrow * 14 + wc] = da[r];
      }
    }
    bar_lgkm();
    prevbase = b0 * 3584 + tile * 224;
  }
  if (prevbase >= 0 && tid < 224) out[prevbase + tid] = obuf[tid];
}

extern "C" void kernel_launch(void* const* d_in, const int* in_sizes, int n_in,
                              void* d_out, int out_size, void* d_ws, size_t ws_size,
                              hipStream_t stream) {
  const float* t = (const float*)d_in[0];
  const float* ctx = (const float*)d_in[1];
  const float* ce_w = (const float*)d_in[2];
  const float* ce_b = (const float*)d_in[3];
  const float* z0_w = (const float*)d_in[4];
  const float* z0_b = (const float*)d_in[5];
  const float* dw0 = (const float*)d_in[6];
  const float* db0 = (const float*)d_in[7];
  const float* dw1 = (const float*)d_in[8];
  const float* db1 = (const float*)d_in[9];
  const float* dw2 = (const float*)d_in[10];
  const float* db2 = (const float*)d_in[11];
  const float* dw3 = (const float*)d_in[12];
  const float* db3 = (const float*)d_in[13];
  const float* dg0 = (const float*)d_in[14];
  const float* dbe0 = (const float*)d_in[15];
  const float* dg1 = (const float*)d_in[16];
  const float* dbe1 = (const float*)d_in[17];
  const float* dg2 = (const float*)d_in[18];
  const float* dbe2 = (const float*)d_in[19];
  const float* ew0 = (const float*)d_in[20];
  const float* eb0 = (const float*)d_in[21];
  const float* ew1 = (const float*)d_in[22];
  const float* eb1 = (const float*)d_in[23];
  const float* ew2 = (const float*)d_in[24];
  const float* eb2 = (const float*)d_in[25];
  const float* ew3 = (const float*)d_in[26];
  const float* eb3 = (const float*)d_in[27];
  const float* eg0 = (const float*)d_in[28];
  const float* ebe0 = (const float*)d_in[29];
  const float* eg1 = (const float*)d_in[30];
  const float* ebe1 = (const float*)d_in[31];
  const float* eg2 = (const float*)d_in[32];
  const float* ebe2 = (const float*)d_in[33];
  float* out = (float*)d_out;

  char* ws = (char*)d_ws;
  u16* wdyn = (u16*)(ws + 0);
  u16* wdec = (u16*)(ws + 122880);
  u16* zt = (u16*)(ws + 208896);
  size_t zt_avail = (ws_size > 208896) ? ws_size - 208896 : 0;

  rlp_pack_all<<<408, 256, 0, stream>>>(dw0, dw1, dw2, dw3, ew0, ew1, ew2, ew3, wdyn, wdec);

  const size_t per_row = (size_t)N_ * 64 * 2;
  int chunkB = B_;
  if (zt_avail < (size_t)B_ * per_row) {
    chunkB = (int)(zt_avail / per_row) & ~7;
    if (chunkB < 8) chunkB = 8;
  }
  for (int b0 = 0; b0 < B_; b0 += chunkB) {
    int cb = (B_ - b0 < chunkB) ? (B_ - b0) : chunkB;
    rlp_scan7<<<cb / 8, 512, 0, stream>>>(t, wdyn, ctx, ce_w, ce_b, z0_w, z0_b,
        db0, db1, db2, db3, dg0, dbe0, dg1, dbe1, dg2, dbe2, zt, b0);
    int ntiles = cb * 16;
    int ngrid = ntiles < 1024 ? ntiles : 1024;
    rlp_dec7<<<ngrid, 512, 0, stream>>>(wdec, zt,
        eb0, eb1, eb2, eb3, eg0, ebe0, eg1, ebe1, eg2, ebe2, out, b0, cb * 256);
  }
}

// Round 8
// 638.572 us; speedup vs baseline: 2.5920x; 1.0888x over previous
//
#include <hip/hip_runtime.h>
#include <cstdint>
#include <cstddef>

#define B_ 2048
#define N_ 256

typedef unsigned short u16;
typedef unsigned int u32;
typedef __attribute__((ext_vector_type(8))) short short8;
typedef __attribute__((ext_vector_type(4))) float floatx4;

__device__ __forceinline__ u16 f2bf(float f) {
  union { float f; unsigned u; } v; v.f = f;
  unsigned u = v.u;
  return (u16)((u + 0x7FFFu + ((u >> 16) & 1u)) >> 16);
}
__device__ __forceinline__ u32 cvt_pk_bf16(float a, float b) {
  u32 r;
  asm("v_cvt_pk_bf16_f32 %0, %1, %2" : "=v"(r) : "v"(a), "v"(b));
  return r;
}
// VALU butterfly adds over lane^16 / lane^32 (replaces ds_swizzle/ds_permute shfl_xor).
// permlaneN_swap(A,B) exchanges A's odd N-rows with B's even N-rows; with A=B=x,
// r[0][l]+r[1][l] == x[l] + x[l^N] on every lane (verified against CDNA4 swap semantics).
__device__ __forceinline__ float bfly16(float x) {
  auto r = __builtin_amdgcn_permlane16_swap(__float_as_int(x), __float_as_int(x), false, false);
  return __int_as_float(r[0]) + __int_as_float(r[1]);
}
__device__ __forceinline__ float bfly32(float x) {
  auto r = __builtin_amdgcn_permlane32_swap(__float_as_int(x), __float_as_int(x), false, false);
  return __int_as_float(r[0]) + __int_as_float(r[1]);
}
#define CC_ 2.885390081777927f  /* 2*log2(e) */
// tanh(x) = 1 - 2/(1 + exp2(x*2log2e)) ; 4 VALU ops, no clamp needed
__device__ __forceinline__ float tanh_fast(float x) {
  float u = __builtin_amdgcn_exp2f(x * CC_);
  return fmaf(__builtin_amdgcn_rcpf(u + 1.0f), -2.0f, 1.0f);
}
// Fourier: sin(pi*t*2^(jj-1)) = v_sin(fract(t*2^(jj-2))) (v_sin takes revolutions; exact pow2 scale)
__device__ __forceinline__ float four_emb(float tv, int j) {
  if (j == 0) return tv;
  int jj = (j <= 8) ? j : j - 8;
  float sc = __int_as_float((jj + 125) << 23);  // 2^(jj-2)
  float r = __builtin_amdgcn_fractf(tv * sc);
  return (j <= 8) ? __builtin_amdgcn_sinf(r) : __builtin_amdgcn_cosf(r);
}
// LDS-only barrier (no vmcnt drain)
__device__ __forceinline__ void bar_lgkm() {
  asm volatile("s_waitcnt lgkmcnt(0)" ::: "memory");
  __builtin_amdgcn_s_barrier();
  __builtin_amdgcn_sched_barrier(0);
}

// ---------------- combined weight packer (one launch).
__global__ void rlp_pack_all(const float* __restrict__ dw0, const float* __restrict__ dw1,
                             const float* __restrict__ dw2, const float* __restrict__ dw3,
                             const float* __restrict__ ew0, const float* __restrict__ ew1,
                             const float* __restrict__ ew2, const float* __restrict__ ew3,
                             u16* __restrict__ wdyn, u16* __restrict__ wdec) {
  int e = blockIdx.x * blockDim.x + threadIdx.x;
  const float* W; int K, Nc, ks, base; u16* dst;
  if (e < 20480)       { W = dw0; K = 145; Nc = 128; ks = 5; dst = wdyn;         base = 0; }
  else if (e < 36864)  { W = dw1; K = 128; Nc = 128; ks = 4; dst = wdyn + 20480; base = 20480; }
  else if (e < 53248)  { W = dw2; K = 128; Nc = 128; ks = 4; dst = wdyn + 36864; base = 36864; }
  else if (e < 61440)  { W = dw3; K = 128; Nc = 64;  ks = 4; dst = wdyn + 53248; base = 53248; }
  else if (e < 69632)  { W = ew0; K = 64;  Nc = 128; ks = 2; dst = wdec;         base = 61440; }
  else if (e < 86016)  { W = ew1; K = 128; Nc = 128; ks = 4; dst = wdec + 8192;  base = 69632; }
  else if (e < 102400) { W = ew2; K = 128; Nc = 128; ks = 4; dst = wdec + 24576; base = 86016; }
  else if (e < 104448) { W = ew3; K = 128; Nc = 14;  ks = 4; dst = wdec + 40960; base = 102400; }
  else return;
  int el = e - base;
  int j = el & 7;
  int lane = (el >> 3) & 63;
  int tt = el >> 9;
  int ksi = tt % ks;
  int nt = tt / ks;
  int col = nt * 16 + (lane & 15);
  int k = ksi * 32 + ((lane >> 4) << 3) + j;
  float v = 0.0f;
  if (k < K && col < Nc) v = W[k * Nc + col];
  dst[el] = f2bf(v);
}

// ---------------- one hidden layer. Av = g*2log2e, Ev = beta*2log2e (folded loop-invariantly).
// Swapped MFMA: A=W frag in VGPR, B=x frag from LDS; C[wcol][brow].
// Cross-lane LN partials via permlane butterflies (VALU); 2 lgkm-barriers.
template <int KS, int KSD, int NROW, int SSTR, int DSTR>
__device__ __forceinline__ void mlp_layer(
    const short8 (&wf)[KS], const short8* xstat, floatx4 bv,
    floatx4 Av, floatx4 Ev,
    const u16* src, u16* dst, float* lnbuf, int wv, int lane) {
  const int rrow = lane & 15;
  const int g = lane >> 4;
  const int srow = (NROW == 8) ? (rrow & 7) : rrow;
  short8 xf[KSD];
#pragma unroll
  for (int ks = 0; ks < KSD; ks++)
    xf[ks] = *reinterpret_cast<const short8*>(&src[srow * SSTR + ks * 32 + g * 8]);
  floatx4 acc = bv;
#pragma unroll
  for (int ks = 0; ks < KSD; ks++)
    acc = __builtin_amdgcn_mfma_f32_16x16x32_bf16(wf[ks], xf[ks], acc, 0, 0, 0);
#pragma unroll
  for (int ks = KSD; ks < KS; ks++)
    acc = __builtin_amdgcn_mfma_f32_16x16x32_bf16(wf[ks], xstat[ks - KSD], acc, 0, 0, 0);
  float s = acc[0] + acc[1] + acc[2] + acc[3];
  float q = acc[0] * acc[0] + acc[1] * acc[1] + acc[2] * acc[2] + acc[3] * acc[3];
  s = bfly32(bfly16(s));
  q = bfly32(bfly16(q));
  if (lane < NROW)
    *reinterpret_cast<float2*>(&lnbuf[lane * 20 + 2 * wv]) = make_float2(s, q);
  bar_lgkm();
  floatx4 p0 = *reinterpret_cast<const floatx4*>(&lnbuf[srow * 20 + 0]);
  floatx4 p1 = *reinterpret_cast<const floatx4*>(&lnbuf[srow * 20 + 4]);
  floatx4 p2 = *reinterpret_cast<const floatx4*>(&lnbuf[srow * 20 + 8]);
  floatx4 p3 = *reinterpret_cast<const floatx4*>(&lnbuf[srow * 20 + 12]);
  float S = p0[0] + p0[2] + p1[0] + p1[2] + p2[0] + p2[2] + p3[0] + p3[2];
  float Q = p0[1] + p0[3] + p1[1] + p1[3] + p2[1] + p2[3] + p3[1] + p3[3];
  float mean = S * 0.0078125f;
  float var = fmaf(Q, 0.0078125f, -mean * mean);
  float rs = __builtin_amdgcn_rsqf(var + 1e-5f);
  float a0 = fmaf((acc[0] - mean) * rs, Av[0], Ev[0]);
  float a1 = fmaf((acc[1] - mean) * rs, Av[1], Ev[1]);
  float a2 = fmaf((acc[2] - mean) * rs, Av[2], Ev[2]);
  float a3 = fmaf((acc[3] - mean) * rs, Av[3], Ev[3]);
  float h0 = fmaf(__builtin_amdgcn_rcpf(__builtin_amdgcn_exp2f(a0) + 1.0f), -2.0f, 1.0f);
  float h1 = fmaf(__builtin_amdgcn_rcpf(__builtin_amdgcn_exp2f(a1) + 1.0f), -2.0f, 1.0f);
  float h2 = fmaf(__builtin_amdgcn_rcpf(__builtin_amdgcn_exp2f(a2) + 1.0f), -2.0f, 1.0f);
  float h3 = fmaf(__builtin_amdgcn_rcpf(__builtin_amdgcn_exp2f(a3) + 1.0f), -2.0f, 1.0f);
  if (rrow < NROW) {
    int f = 16 * wv + 4 * g;
    uint2 hp = make_uint2(cvt_pk_bf16(h0, h1), cvt_pk_bf16(h2, h3));
    *reinterpret_cast<uint2*>(&dst[rrow * DSTR + f]) = hp;
  }
  bar_lgkm();
}

// ---------------- scan: 512 threads (8 waves), 8 rows/WG, grid 256.
__global__ __launch_bounds__(512, 1) void rlp_scan8(
    const float* __restrict__ t, const u16* __restrict__ wdyn,
    const float* __restrict__ ctxg, const float* __restrict__ cew,
    const float* __restrict__ ceb, const float* __restrict__ z0w,
    const float* __restrict__ z0b,
    const float* __restrict__ db0, const float* __restrict__ db1,
    const float* __restrict__ db2, const float* __restrict__ db3,
    const float* __restrict__ dg0, const float* __restrict__ dbe0,
    const float* __restrict__ dg1, const float* __restrict__ dbe1,
    const float* __restrict__ dg2, const float* __restrict__ dbe2,
    u16* __restrict__ ztraj, int b0) {
  __shared__ __align__(16) u16 xb[8][168];
  __shared__ __align__(16) u16 hA[8][168];
  __shared__ __align__(16) u16 hB[8][168];
  __shared__ __align__(16) float lnS[8 * 20];
  __shared__ __align__(16) float tl[8][260];
  __shared__ float ctxe[8][64];
  __shared__ float zbuf[8][64];

  const int tid = threadIdx.x;
  const int wv = tid >> 6;
  const int lane = tid & 63;
  const int rrow = lane & 15;
  const int g = lane >> 4;
  const int r8 = rrow & 7;
  const int w4 = wv & 3;
  const int fb = 16 * wv + 4 * g;
  const int fb4 = 16 * w4 + 4 * g;
  const int gb = b0 + blockIdx.x * 8;

  const floatx4 b1 = *(const floatx4*)&db0[fb];
  const floatx4 g1v = *(const floatx4*)&dg0[fb];
  const floatx4 e1v = *(const floatx4*)&dbe0[fb];
  const floatx4 b2 = *(const floatx4*)&db1[fb];
  const floatx4 g2v = *(const floatx4*)&dg1[fb];
  const floatx4 e2v = *(const floatx4*)&dbe1[fb];
  const floatx4 b3 = *(const floatx4*)&db2[fb];
  const floatx4 g3v = *(const floatx4*)&dg2[fb];
  const floatx4 e3v = *(const floatx4*)&dbe2[fb];
  const floatx4 b4 = *(const floatx4*)&db3[fb4];
  const floatx4 A1 = {g1v[0] * CC_, g1v[1] * CC_, g1v[2] * CC_, g1v[3] * CC_};
  const floatx4 E1 = {e1v[0] * CC_, e1v[1] * CC_, e1v[2] * CC_, e1v[3] * CC_};
  const floatx4 A2 = {g2v[0] * CC_, g2v[1] * CC_, g2v[2] * CC_, g2v[3] * CC_};
  const floatx4 E2 = {e2v[0] * CC_, e2v[1] * CC_, e2v[2] * CC_, e2v[3] * CC_};
  const floatx4 A3 = {g3v[0] * CC_, g3v[1] * CC_, g3v[2] * CC_, g3v[3] * CC_};
  const floatx4 E3 = {e3v[0] * CC_, e3v[1] * CC_, e3v[2] * CC_, e3v[3] * CC_};

  short8 wf1[5], wf2[4], wf3[4], wf4[4];
#pragma unroll
  for (int ks = 0; ks < 5; ks++)
    wf1[ks] = *(const short8*)(wdyn + ((size_t)(wv * 5 + ks) * 64 + lane) * 8);
#pragma unroll
  for (int ks = 0; ks < 4; ks++)
    wf2[ks] = *(const short8*)(wdyn + 20480 + ((size_t)(wv * 4 + ks) * 64 + lane) * 8);
#pragma unroll
  for (int ks = 0; ks < 4; ks++)
    wf3[ks] = *(const short8*)(wdyn + 36864 + ((size_t)(wv * 4 + ks) * 64 + lane) * 8);
#pragma unroll
  for (int ks = 0; ks < 4; ks++)
    wf4[ks] = *(const short8*)(wdyn + 53248 + ((size_t)(w4 * 4 + ks) * 64 + lane) * 8);

  for (int i = tid; i < 8 * 256; i += 512) {
    int r = i >> 8, c = i & 255;
    tl[r][c] = t[(size_t)(gb + r) * N_ + c];
  }
  for (int i = tid; i < 8 * 168 / 2; i += 512) reinterpret_cast<u32*>(&xb[0][0])[i] = 0;
  __syncthreads();

  {
    int b = tid >> 6, c = tid & 63;
    float s = ceb[c];
#pragma unroll
    for (int k = 0; k < 32; k++) s += ctxg[(size_t)(gb + b) * 32 + k] * cew[k * 64 + c];
    float v = tanh_fast(s);
    ctxe[b][c] = v;
    xb[b][81 + c] = f2bf(v);
  }
  __syncthreads();
  {
    int b = tid >> 6, l = tid & 63;
    float s = z0b[l];
#pragma unroll 8
    for (int k = 0; k < 64; k++) s += ctxe[b][k] * z0w[k * 64 + l];
    zbuf[b][l] = tanh_fast(s);
  }
  if (tid < 136) {
    int b = tid / 17, j = tid - b * 17;
    xb[b][64 + j] = f2bf(four_emb(tl[b][0], j));
  }
  __syncthreads();

  float zr0, zr1, zr2, zr3;
  {
    const floatx4 zv = *(const floatx4*)&zbuf[r8][fb4];
    zr0 = zv[0]; zr1 = zv[1]; zr2 = zv[2]; zr3 = zv[3];
    if (wv < 4 && rrow < 8) {
      uint2 zp = make_uint2(cvt_pk_bf16(zr0, zr1), cvt_pk_bf16(zr2, zr3));
      *reinterpret_cast<uint2*>(&xb[rrow][fb4]) = zp;
      size_t zi = ((size_t)(blockIdx.x * 8 + rrow) * N_) * 64 + fb4;
      *reinterpret_cast<uint2*>(&ztraj[zi]) = zp;
    }
  }
  __syncthreads();

  short8 xs[2];
  xs[0] = *reinterpret_cast<const short8*>(&xb[r8][96 + g * 8]);
  xs[1] = *reinterpret_cast<const short8*>(&xb[r8][128 + g * 8]);

  for (int n = 0; n < N_ - 1; n++) {
    mlp_layer<5, 3, 8, 168, 168>(wf1, xs, b1, A1, E1, &xb[0][0], &hA[0][0], lnS, wv, lane);
    mlp_layer<4, 4, 8, 168, 168>(wf2, nullptr, b2, A2, E2, &hA[0][0], &hB[0][0], lnS, wv, lane);
    mlp_layer<4, 4, 8, 168, 168>(wf3, nullptr, b3, A3, E3, &hB[0][0], &hA[0][0], lnS, wv, lane);
    if (wv < 4) {
      short8 xf[4];
#pragma unroll
      for (int ks = 0; ks < 4; ks++)
        xf[ks] = *reinterpret_cast<const short8*>(&hA[r8][ks * 32 + g * 8]);
      floatx4 da = b4;
#pragma unroll
      for (int ks = 0; ks < 4; ks++)
        da = __builtin_amdgcn_mfma_f32_16x16x32_bf16(wf4[ks], xf[ks], da, 0, 0, 0);
      float dt = tl[r8][n + 1] - tl[r8][n];
      zr0 += dt * da[0]; zr1 += dt * da[1]; zr2 += dt * da[2]; zr3 += dt * da[3];
      if (rrow < 8) {
        uint2 zp = make_uint2(cvt_pk_bf16(zr0, zr1), cvt_pk_bf16(zr2, zr3));
        *reinterpret_cast<uint2*>(&xb[rrow][fb4]) = zp;
        size_t zi = ((size_t)(blockIdx.x * 8 + rrow) * N_ + (n + 1)) * 64 + fb4;
        *reinterpret_cast<uint2*>(&ztraj[zi]) = zp;
      }
    } else {
      int t2 = tid - 256;
      if (t2 < 136 && n < N_ - 2) {
        int b = t2 / 17, j = t2 - b * 17;
        xb[b][64 + j] = f2bf(four_emb(tl[b][n + 1], j));
      }
    }
    bar_lgkm();
  }
}

// ---------------- decoder: 512 threads, 4 blocks/CU, 16 rows/iter, grid-stride.
__global__ __launch_bounds__(512, 4) void rlp_dec8(
    const u16* __restrict__ wdec, const u16* __restrict__ ztraj,
    const float* __restrict__ eb0, const float* __restrict__ eb1,
    const float* __restrict__ eb2, const float* __restrict__ eb3,
    const float* __restrict__ eg0, const float* __restrict__ ebe0,
    const float* __restrict__ eg1, const float* __restrict__ ebe1,
    const float* __restrict__ eg2, const float* __restrict__ ebe2,
    float* __restrict__ out, int b0, int nrows) {
  __shared__ __align__(16) u16 xz[16][72];
  __shared__ __align__(16) u16 hA[16][168];
  __shared__ __align__(16) u16 hB[16][168];
  __shared__ __align__(16) float lnD[16 * 20];
  __shared__ float obuf[224];
  __shared__ float bias1[128], bias2[128], bias3[128], bias4[16];
  __shared__ float g1s[128], e1s[128], g2s[128], e2s[128], g3s[128], e3s[128];

  const int tid = threadIdx.x;
  const int wv = tid >> 6;
  const int lane = tid & 63;
  const int rrow = lane & 15;
  const int g = lane >> 4;
  const int fb = 16 * wv + 4 * g;

  short8 wf1[2], wf2[4], wf3[4], wf4[4];
#pragma unroll
  for (int ks = 0; ks < 2; ks++)
    wf1[ks] = *(const short8*)(wdec + ((size_t)(wv * 2 + ks) * 64 + lane) * 8);
#pragma unroll
  for (int ks = 0; ks < 4; ks++)
    wf2[ks] = *(const short8*)(wdec + 8192 + ((size_t)(wv * 4 + ks) * 64 + lane) * 8);
#pragma unroll
  for (int ks = 0; ks < 4; ks++)
    wf3[ks] = *(const short8*)(wdec + 24576 + ((size_t)(wv * 4 + ks) * 64 + lane) * 8);
#pragma unroll
  for (int ks = 0; ks < 4; ks++)
    wf4[ks] = *(const short8*)(wdec + 40960 + ((size_t)ks * 64 + lane) * 8);

  for (int i = tid; i < 128; i += 512) {
    bias1[i] = eb0[i]; bias2[i] = eb1[i]; bias3[i] = eb2[i];
    g1s[i] = eg0[i]; e1s[i] = ebe0[i];
    g2s[i] = eg1[i]; e2s[i] = ebe1[i];
    g3s[i] = eg2[i]; e3s[i] = ebe2[i];
  }
  if (tid < 16) bias4[tid] = (tid < 14) ? eb3[tid] : 0.0f;
  __syncthreads();

  const floatx4 b1 = *(const floatx4*)&bias1[fb];
  const floatx4 g1v = *(const floatx4*)&g1s[fb];
  const floatx4 e1v = *(const floatx4*)&e1s[fb];
  const floatx4 b2 = *(const floatx4*)&bias2[fb];
  const floatx4 g2v = *(const floatx4*)&g2s[fb];
  const floatx4 e2v = *(const floatx4*)&e2s[fb];
  const floatx4 b3 = *(const floatx4*)&bias3[fb];
  const floatx4 g3v = *(const floatx4*)&g3s[fb];
  const floatx4 e3v = *(const floatx4*)&e3s[fb];
  const floatx4 b4 = *(const floatx4*)&bias4[4 * g];
  const floatx4 A1 = {g1v[0] * CC_, g1v[1] * CC_, g1v[2] * CC_, g1v[3] * CC_};
  const floatx4 E1 = {e1v[0] * CC_, e1v[1] * CC_, e1v[2] * CC_, e1v[3] * CC_};
  const floatx4 A2 = {g2v[0] * CC_, g2v[1] * CC_, g2v[2] * CC_, g2v[3] * CC_};
  const floatx4 E2 = {e2v[0] * CC_, e2v[1] * CC_, e2v[2] * CC_, e2v[3] * CC_};
  const floatx4 A3 = {g3v[0] * CC_, g3v[1] * CC_, g3v[2] * CC_, g3v[3] * CC_};
  const floatx4 E3 = {e3v[0] * CC_, e3v[1] * CC_, e3v[2] * CC_, e3v[3] * CC_};

  const int ntiles = nrows >> 4;
  int prevbase = -1;
  for (int tile = blockIdx.x; tile < ntiles; tile += gridDim.x) {
    if (prevbase >= 0 && tid < 224) out[prevbase + tid] = obuf[tid];
    if (tid < 128) {
      int rr = tid >> 3, p = tid & 7;
      *reinterpret_cast<short8*>(&xz[rr][p * 8]) =
          *reinterpret_cast<const short8*>(&ztraj[(size_t)(tile * 16 + rr) * 64 + p * 8]);
    }
    bar_lgkm();
    mlp_layer<2, 2, 16, 72, 168>(wf1, nullptr, b1, A1, E1, &xz[0][0], &hA[0][0], lnD, wv, lane);
    mlp_layer<4, 4, 16, 168, 168>(wf2, nullptr, b2, A2, E2, &hA[0][0], &hB[0][0], lnD, wv, lane);
    mlp_layer<4, 4, 16, 168, 168>(wf3, nullptr, b3, A3, E3, &hB[0][0], &hA[0][0], lnD, wv, lane);
    if (wv == 0) {
      short8 xf[4];
#pragma unroll
      for (int ks = 0; ks < 4; ks++)
        xf[ks] = *reinterpret_cast<const short8*>(&hA[rrow][ks * 32 + g * 8]);
      floatx4 da = b4;
#pragma unroll
      for (int ks = 0; ks < 4; ks++)
        da = __builtin_amdgcn_mfma_f32_16x16x32_bf16(wf4[ks], xf[ks], da, 0, 0, 0);
#pragma unroll
      for (int r = 0; r < 4; r++) {
        int wc = 4 * g + r;
        if (wc < 14) obuf[rrow * 14 + wc] = da[r];
      }
    }
    bar_lgkm();
    prevbase = b0 * 3584 + tile * 224;
  }
  if (prevbase >= 0 && tid < 224) out[prevbase + tid] = obuf[tid];
}

extern "C" void kernel_launch(void* const* d_in, const int* in_sizes, int n_in,
                              void* d_out, int out_size, void* d_ws, size_t ws_size,
                              hipStream_t stream) {
  const float* t = (const float*)d_in[0];
  const float* ctx = (const float*)d_in[1];
  const float* ce_w = (const float*)d_in[2];
  const float* ce_b = (const float*)d_in[3];
  const float* z0_w = (const float*)d_in[4];
  const float* z0_b = (const float*)d_in[5];
  const float* dw0 = (const float*)d_in[6];
  const float* db0 = (const float*)d_in[7];
  const float* dw1 = (const float*)d_in[8];
  const float* db1 = (const float*)d_in[9];
  const float* dw2 = (const float*)d_in[10];
  const float* db2 = (const float*)d_in[11];
  const float* dw3 = (const float*)d_in[12];
  const float* db3 = (const float*)d_in[13];
  const float* dg0 = (const float*)d_in[14];
  const float* dbe0 = (const float*)d_in[15];
  const float* dg1 = (const float*)d_in[16];
  const float* dbe1 = (const float*)d_in[17];
  const float* dg2 = (const float*)d_in[18];
  const float* dbe2 = (const float*)d_in[19];
  const float* ew0 = (const float*)d_in[20];
  const float* eb0 = (const float*)d_in[21];
  const float* ew1 = (const float*)d_in[22];
  const float* eb1 = (const float*)d_in[23];
  const float* ew2 = (const float*)d_in[24];
  const float* eb2 = (const float*)d_in[25];
  const float* ew3 = (const float*)d_in[26];
  const float* eb3 = (const float*)d_in[27];
  const float* eg0 = (const float*)d_in[28];
  const float* ebe0 = (const float*)d_in[29];
  const float* eg1 = (const float*)d_in[30];
  const float* ebe1 = (const float*)d_in[31];
  const float* eg2 = (const float*)d_in[32];
  const float* ebe2 = (const float*)d_in[33];
  float* out = (float*)d_out;

  char* ws = (char*)d_ws;
  u16* wdyn = (u16*)(ws + 0);
  u16* wdec = (u16*)(ws + 122880);
  u16* zt = (u16*)(ws + 208896);
  size_t zt_avail = (ws_size > 208896) ? ws_size - 208896 : 0;

  rlp_pack_all<<<408, 256, 0, stream>>>(dw0, dw1, dw2, dw3, ew0, ew1, ew2, ew3, wdyn, wdec);

  const size_t per_row = (size_t)N_ * 64 * 2;
  int chunkB = B_;
  if (zt_avail < (size_t)B_ * per_row) {
    chunkB = (int)(zt_avail / per_row) & ~7;
    if (chunkB < 8) chunkB = 8;
  }
  for (int b0 = 0; b0 < B_; b0 += chunkB) {
    int cb = (B_ - b0 < chunkB) ? (B_ - b0) : chunkB;
    rlp_scan8<<<cb / 8, 512, 0, stream>>>(t, wdyn, ctx, ce_w, ce_b, z0_w, z0_b,
        db0, db1, db2, db3, dg0, dbe0, dg1, dbe1, dg2, dbe2, zt, b0);
    int ntiles = cb * 16;
    int ngrid = ntiles < 1024 ? ntiles : 1024;
    rlp_dec8<<<ngrid, 512, 0, stream>>>(wdec, zt,
        eb0, eb1, eb2, eb3, eg0, ebe0, eg1, ebe1, eg2, ebe2, out, b0, cb * 256);
  }
}

// Round 9
// 572.412 us; speedup vs baseline: 2.8916x; 1.1156x over previous
//
#include <hip/hip_runtime.h>
#include <cstdint>
#include <cstddef>

#define B_ 2048
#define N_ 256

typedef unsigned short u16;
typedef unsigned int u32;
typedef __attribute__((ext_vector_type(8))) short short8;
typedef __attribute__((ext_vector_type(4))) float floatx4;

__device__ __forceinline__ u16 f2bf(float f) {
  union { float f; unsigned u; } v; v.f = f;
  unsigned u = v.u;
  return (u16)((u + 0x7FFFu + ((u >> 16) & 1u)) >> 16);
}
__device__ __forceinline__ u32 cvt_pk_bf16(float a, float b) {
  u32 r;
  asm("v_cvt_pk_bf16_f32 %0, %1, %2" : "=v"(r) : "v"(a), "v"(b));
  return r;
}
// VALU butterfly adds over lane^16 / lane^32 (proven bit-exact in R8)
__device__ __forceinline__ float bfly16(float x) {
  auto r = __builtin_amdgcn_permlane16_swap(__float_as_int(x), __float_as_int(x), false, false);
  return __int_as_float(r[0]) + __int_as_float(r[1]);
}
__device__ __forceinline__ float bfly32(float x) {
  auto r = __builtin_amdgcn_permlane32_swap(__float_as_int(x), __float_as_int(x), false, false);
  return __int_as_float(r[0]) + __int_as_float(r[1]);
}
#define CC_ 2.885390081777927f  /* 2*log2(e) */
__device__ __forceinline__ float tanh_fast(float x) {
  float u = __builtin_amdgcn_exp2f(x * CC_);
  return fmaf(__builtin_amdgcn_rcpf(u + 1.0f), -2.0f, 1.0f);
}
__device__ __forceinline__ float four_emb(float tv, int j) {
  if (j == 0) return tv;
  int jj = (j <= 8) ? j : j - 8;
  float sc = __int_as_float((jj + 125) << 23);  // 2^(jj-2)
  float r = __builtin_amdgcn_fractf(tv * sc);
  return (j <= 8) ? __builtin_amdgcn_sinf(r) : __builtin_amdgcn_cosf(r);
}
__device__ __forceinline__ void bar_lgkm() {
  asm volatile("s_waitcnt lgkmcnt(0)" ::: "memory");
  __builtin_amdgcn_s_barrier();
  __builtin_amdgcn_sched_barrier(0);
}

// ---------------- combined weight packer (one launch).
__global__ void rlp_pack_all(const float* __restrict__ dw0, const float* __restrict__ dw1,
                             const float* __restrict__ dw2, const float* __restrict__ dw3,
                             const float* __restrict__ ew0, const float* __restrict__ ew1,
                             const float* __restrict__ ew2, const float* __restrict__ ew3,
                             u16* __restrict__ wdyn, u16* __restrict__ wdec) {
  int e = blockIdx.x * blockDim.x + threadIdx.x;
  const float* W; int K, Nc, ks, base; u16* dst;
  if (e < 20480)       { W = dw0; K = 145; Nc = 128; ks = 5; dst = wdyn;         base = 0; }
  else if (e < 36864)  { W = dw1; K = 128; Nc = 128; ks = 4; dst = wdyn + 20480; base = 20480; }
  else if (e < 53248)  { W = dw2; K = 128; Nc = 128; ks = 4; dst = wdyn + 36864; base = 36864; }
  else if (e < 61440)  { W = dw3; K = 128; Nc = 64;  ks = 4; dst = wdyn + 53248; base = 53248; }
  else if (e < 69632)  { W = ew0; K = 64;  Nc = 128; ks = 2; dst = wdec;         base = 61440; }
  else if (e < 86016)  { W = ew1; K = 128; Nc = 128; ks = 4; dst = wdec + 8192;  base = 69632; }
  else if (e < 102400) { W = ew2; K = 128; Nc = 128; ks = 4; dst = wdec + 24576; base = 86016; }
  else if (e < 104448) { W = ew3; K = 128; Nc = 14;  ks = 4; dst = wdec + 40960; base = 102400; }
  else return;
  int el = e - base;
  int j = el & 7;
  int lane = (el >> 3) & 63;
  int tt = el >> 9;
  int ksi = tt % ks;
  int nt = tt / ks;
  int col = nt * 16 + (lane & 15);
  int k = ksi * 32 + ((lane >> 4) << 3) + j;
  float v = 0.0f;
  if (k < K && col < Nc) v = W[k * Nc + col];
  dst[el] = f2bf(v);
}

// ---------------- one hidden layer, 2 col-tiles per wave (wave covers cols [32wl,32wl+32)).
// Group's 4 waves cover 128 cols; LN partial exchange within group (grpoff selects slots).
template <int KS, int KSD>
__device__ __forceinline__ void mlp_layer2(
    const short8* wT0, const short8* wT1, const short8* xstat,
    floatx4 bv0, floatx4 bv1,
    floatx4 A0, floatx4 E0, floatx4 A1, floatx4 E1,
    const u16* src, u16* dst, float* lnbuf, int grpoff, int wl, int lane) {
  const int rrow = lane & 15;
  const int g = lane >> 4;
  const int srow = rrow & 7;
  short8 xf[KSD];
#pragma unroll
  for (int ks = 0; ks < KSD; ks++)
    xf[ks] = *reinterpret_cast<const short8*>(&src[srow * 168 + ks * 32 + g * 8]);
  floatx4 acc0 = bv0, acc1 = bv1;
#pragma unroll
  for (int ks = 0; ks < KSD; ks++) {
    acc0 = __builtin_amdgcn_mfma_f32_16x16x32_bf16(wT0[ks], xf[ks], acc0, 0, 0, 0);
    acc1 = __builtin_amdgcn_mfma_f32_16x16x32_bf16(wT1[ks], xf[ks], acc1, 0, 0, 0);
  }
#pragma unroll
  for (int ks = KSD; ks < KS; ks++) {
    acc0 = __builtin_amdgcn_mfma_f32_16x16x32_bf16(wT0[ks], xstat[ks - KSD], acc0, 0, 0, 0);
    acc1 = __builtin_amdgcn_mfma_f32_16x16x32_bf16(wT1[ks], xstat[ks - KSD], acc1, 0, 0, 0);
  }
  float s = ((acc0[0] + acc0[1]) + (acc0[2] + acc0[3]))
          + ((acc1[0] + acc1[1]) + (acc1[2] + acc1[3]));
  float q = ((acc0[0] * acc0[0] + acc0[1] * acc0[1]) + (acc0[2] * acc0[2] + acc0[3] * acc0[3]))
          + ((acc1[0] * acc1[0] + acc1[1] * acc1[1]) + (acc1[2] * acc1[2] + acc1[3] * acc1[3]));
  s = bfly32(bfly16(s));
  q = bfly32(bfly16(q));
  if (lane < 8)
    *reinterpret_cast<float2*>(&lnbuf[lane * 20 + grpoff + 2 * wl]) = make_float2(s, q);
  bar_lgkm();
  floatx4 p0 = *reinterpret_cast<const floatx4*>(&lnbuf[srow * 20 + grpoff + 0]);
  floatx4 p1 = *reinterpret_cast<const floatx4*>(&lnbuf[srow * 20 + grpoff + 4]);
  float S = (p0[0] + p0[2]) + (p1[0] + p1[2]);
  float Q = (p0[1] + p0[3]) + (p1[1] + p1[3]);
  float mean = S * 0.0078125f;
  float var = fmaf(Q, 0.0078125f, -mean * mean);
  float rs = __builtin_amdgcn_rsqf(var + 1e-5f);
  float a0 = fmaf((acc0[0] - mean) * rs, A0[0], E0[0]);
  float a1 = fmaf((acc0[1] - mean) * rs, A0[1], E0[1]);
  float a2 = fmaf((acc0[2] - mean) * rs, A0[2], E0[2]);
  float a3 = fmaf((acc0[3] - mean) * rs, A0[3], E0[3]);
  float c0 = fmaf((acc1[0] - mean) * rs, A1[0], E1[0]);
  float c1 = fmaf((acc1[1] - mean) * rs, A1[1], E1[1]);
  float c2 = fmaf((acc1[2] - mean) * rs, A1[2], E1[2]);
  float c3 = fmaf((acc1[3] - mean) * rs, A1[3], E1[3]);
  float h0 = fmaf(__builtin_amdgcn_rcpf(__builtin_amdgcn_exp2f(a0) + 1.0f), -2.0f, 1.0f);
  float h1 = fmaf(__builtin_amdgcn_rcpf(__builtin_amdgcn_exp2f(a1) + 1.0f), -2.0f, 1.0f);
  float h2 = fmaf(__builtin_amdgcn_rcpf(__builtin_amdgcn_exp2f(a2) + 1.0f), -2.0f, 1.0f);
  float h3 = fmaf(__builtin_amdgcn_rcpf(__builtin_amdgcn_exp2f(a3) + 1.0f), -2.0f, 1.0f);
  float h4 = fmaf(__builtin_amdgcn_rcpf(__builtin_amdgcn_exp2f(c0) + 1.0f), -2.0f, 1.0f);
  float h5 = fmaf(__builtin_amdgcn_rcpf(__builtin_amdgcn_exp2f(c1) + 1.0f), -2.0f, 1.0f);
  float h6 = fmaf(__builtin_amdgcn_rcpf(__builtin_amdgcn_exp2f(c2) + 1.0f), -2.0f, 1.0f);
  float h7 = fmaf(__builtin_amdgcn_rcpf(__builtin_amdgcn_exp2f(c3) + 1.0f), -2.0f, 1.0f);
  if (rrow < 8) {
    *reinterpret_cast<uint2*>(&dst[rrow * 168 + 32 * wl + 4 * g]) =
        make_uint2(cvt_pk_bf16(h0, h1), cvt_pk_bf16(h2, h3));
    *reinterpret_cast<uint2*>(&dst[rrow * 168 + 32 * wl + 16 + 4 * g]) =
        make_uint2(cvt_pk_bf16(h4, h5), cvt_pk_bf16(h6, h7));
  }
  bar_lgkm();
}

// ---------------- fused scan+decode: waves 0-3 dynamics, waves 4-7 decoder(z_n).
// 8 rows/WG, grid 256, 512 threads. Weights in registers. No ztraj.
__global__ __launch_bounds__(512, 1) void rlp_fused(
    const float* __restrict__ t,
    const u16* __restrict__ wdyn, const u16* __restrict__ wdec,
    const float* __restrict__ ctxg, const float* __restrict__ cew,
    const float* __restrict__ ceb, const float* __restrict__ z0w,
    const float* __restrict__ z0b,
    const float* __restrict__ db0, const float* __restrict__ db1,
    const float* __restrict__ db2, const float* __restrict__ db3,
    const float* __restrict__ dg0, const float* __restrict__ dbe0,
    const float* __restrict__ dg1, const float* __restrict__ dbe1,
    const float* __restrict__ dg2, const float* __restrict__ dbe2,
    const float* __restrict__ eb0, const float* __restrict__ eb1,
    const float* __restrict__ eb2, const float* __restrict__ eb3,
    const float* __restrict__ eg0, const float* __restrict__ ebe0,
    const float* __restrict__ eg1, const float* __restrict__ ebe1,
    const float* __restrict__ eg2, const float* __restrict__ ebe2,
    float* __restrict__ out) {
  __shared__ __align__(16) u16 xb[8 * 168];   // 0-63 z | 64-80 temb | 81-144 ctx | 145-167 zero
  __shared__ __align__(16) u16 hdA[8 * 168];
  __shared__ __align__(16) u16 hdB[8 * 168];
  __shared__ __align__(16) u16 heA[8 * 168];
  __shared__ __align__(16) u16 heB[8 * 168];
  __shared__ __align__(16) float lnS[8 * 20];  // [row][dyn 0-7 | dec 8-15]
  __shared__ __align__(16) float tl[8][260];
  __shared__ float ctxe[8][64];
  __shared__ float zbuf[8][64];

  const int tid = threadIdx.x;
  const int wv = tid >> 6;
  const int lane = tid & 63;
  const int rrow = lane & 15;
  const int g = lane >> 4;
  const int r8 = rrow & 7;
  const int wl = wv & 3;
  const bool isdyn = (wv < 4);
  const int grpoff = isdyn ? 0 : 8;
  const int gb = blockIdx.x * 8;

  // ---- group-selected parameter pointers (identical code paths after this)
  const float* pb1 = isdyn ? db0 : eb0;
  const float* pg1 = isdyn ? dg0 : eg0;
  const float* pe1 = isdyn ? dbe0 : ebe0;
  const float* pb2 = isdyn ? db1 : eb1;
  const float* pg2 = isdyn ? dg1 : eg1;
  const float* pe2 = isdyn ? dbe1 : ebe1;
  const float* pb3 = isdyn ? db2 : eb2;
  const float* pg3 = isdyn ? dg2 : eg2;
  const float* pe3 = isdyn ? dbe2 : ebe2;

  const int c0 = 32 * wl + 4 * g;          // tile0 col base for this lane
  const floatx4 b1t0 = *(const floatx4*)&pb1[c0];
  const floatx4 b1t1 = *(const floatx4*)&pb1[c0 + 16];
  const floatx4 g1t0 = *(const floatx4*)&pg1[c0];
  const floatx4 g1t1 = *(const floatx4*)&pg1[c0 + 16];
  const floatx4 e1t0 = *(const floatx4*)&pe1[c0];
  const floatx4 e1t1 = *(const floatx4*)&pe1[c0 + 16];
  const floatx4 b2t0 = *(const floatx4*)&pb2[c0];
  const floatx4 b2t1 = *(const floatx4*)&pb2[c0 + 16];
  const floatx4 g2t0 = *(const floatx4*)&pg2[c0];
  const floatx4 g2t1 = *(const floatx4*)&pg2[c0 + 16];
  const floatx4 e2t0 = *(const floatx4*)&pe2[c0];
  const floatx4 e2t1 = *(const floatx4*)&pe2[c0 + 16];
  const floatx4 b3t0 = *(const floatx4*)&pb3[c0];
  const floatx4 b3t1 = *(const floatx4*)&pb3[c0 + 16];
  const floatx4 g3t0 = *(const floatx4*)&pg3[c0];
  const floatx4 g3t1 = *(const floatx4*)&pg3[c0 + 16];
  const floatx4 e3t0 = *(const floatx4*)&pe3[c0];
  const floatx4 e3t1 = *(const floatx4*)&pe3[c0 + 16];
#define FOLD(v) {v[0] * CC_, v[1] * CC_, v[2] * CC_, v[3] * CC_}
  const floatx4 A1t0 = FOLD(g1t0), A1t1 = FOLD(g1t1), E1t0 = FOLD(e1t0), E1t1 = FOLD(e1t1);
  const floatx4 A2t0 = FOLD(g2t0), A2t1 = FOLD(g2t1), E2t0 = FOLD(e2t0), E2t1 = FOLD(e2t1);
  const floatx4 A3t0 = FOLD(g3t0), A3t1 = FOLD(g3t1), E3t0 = FOLD(e3t0), E3t1 = FOLD(e3t1);
#undef FOLD
  floatx4 b4;
  if (isdyn) {
    b4 = *(const floatx4*)&db3[16 * wl + 4 * g];
  } else {
    int cb = 4 * g;
    b4[0] = (cb + 0 < 14) ? eb3[cb + 0] : 0.0f;
    b4[1] = (cb + 1 < 14) ? eb3[cb + 1] : 0.0f;
    b4[2] = (cb + 2 < 14) ? eb3[cb + 2] : 0.0f;
    b4[3] = (cb + 3 < 14) ? eb3[cb + 3] : 0.0f;
  }

  // ---- weight fragments: wA/wB = tiles 2wl / 2wl+1; slots [0-4]=L1, [5-8]=L2, [9-12]=L3.
  short8 wA[13], wB[13], w4[4];
  if (isdyn) {
#pragma unroll
    for (int ks = 0; ks < 5; ks++) {
      wA[ks] = *(const short8*)(wdyn + ((size_t)((2 * wl + 0) * 5 + ks) * 64 + lane) * 8);
      wB[ks] = *(const short8*)(wdyn + ((size_t)((2 * wl + 1) * 5 + ks) * 64 + lane) * 8);
    }
#pragma unroll
    for (int ks = 0; ks < 4; ks++) {
      wA[5 + ks] = *(const short8*)(wdyn + 20480 + ((size_t)((2 * wl + 0) * 4 + ks) * 64 + lane) * 8);
      wB[5 + ks] = *(const short8*)(wdyn + 20480 + ((size_t)((2 * wl + 1) * 4 + ks) * 64 + lane) * 8);
      wA[9 + ks] = *(const short8*)(wdyn + 36864 + ((size_t)((2 * wl + 0) * 4 + ks) * 64 + lane) * 8);
      wB[9 + ks] = *(const short8*)(wdyn + 36864 + ((size_t)((2 * wl + 1) * 4 + ks) * 64 + lane) * 8);
      w4[ks] = *(const short8*)(wdyn + 53248 + ((size_t)(wl * 4 + ks) * 64 + lane) * 8);
    }
  } else {
#pragma unroll
    for (int ks = 0; ks < 2; ks++) {
      wA[ks] = *(const short8*)(wdec + ((size_t)((2 * wl + 0) * 2 + ks) * 64 + lane) * 8);
      wB[ks] = *(const short8*)(wdec + ((size_t)((2 * wl + 1) * 2 + ks) * 64 + lane) * 8);
    }
#pragma unroll
    for (int ks = 0; ks < 4; ks++) {
      wA[5 + ks] = *(const short8*)(wdec + 8192 + ((size_t)((2 * wl + 0) * 4 + ks) * 64 + lane) * 8);
      wB[5 + ks] = *(const short8*)(wdec + 8192 + ((size_t)((2 * wl + 1) * 4 + ks) * 64 + lane) * 8);
      wA[9 + ks] = *(const short8*)(wdec + 24576 + ((size_t)((2 * wl + 0) * 4 + ks) * 64 + lane) * 8);
      wB[9 + ks] = *(const short8*)(wdec + 24576 + ((size_t)((2 * wl + 1) * 4 + ks) * 64 + lane) * 8);
      w4[ks] = *(const short8*)(wdec + 40960 + ((size_t)ks * 64 + lane) * 8);
    }
  }
  u16* h0 = isdyn ? hdA : heA;
  u16* h1 = isdyn ? hdB : heB;

  // ---- prologue: t -> LDS, zero xb, ctx encoder, z0 encoder, temb(0)
  for (int i = tid; i < 8 * 256; i += 512) {
    int r = i >> 8, c = i & 255;
    tl[r][c] = t[(size_t)(gb + r) * N_ + c];
  }
  for (int i = tid; i < 8 * 168 / 2; i += 512) reinterpret_cast<u32*>(&xb[0])[i] = 0;
  __syncthreads();
  {
    int b = tid >> 6, c = tid & 63;
    float s = ceb[c];
#pragma unroll
    for (int k = 0; k < 32; k++) s += ctxg[(size_t)(gb + b) * 32 + k] * cew[k * 64 + c];
    float v = tanh_fast(s);
    ctxe[b][c] = v;
    xb[b * 168 + 81 + c] = f2bf(v);
  }
  __syncthreads();
  {
    int b = tid >> 6, l = tid & 63;
    float s = z0b[l];
#pragma unroll 8
    for (int k = 0; k < 64; k++) s += ctxe[b][k] * z0w[k * 64 + l];
    zbuf[b][l] = tanh_fast(s);
  }
  if (tid < 136) {
    int b = tid / 17, j = tid - b * 17;
    xb[b * 168 + 64 + j] = f2bf(four_emb(tl[b][0], j));
  }
  __syncthreads();

  // z0 into dyn registers + xb
  float zr0, zr1, zr2, zr3;
  {
    const floatx4 zv = *(const floatx4*)&zbuf[r8][16 * wl + 4 * g];
    zr0 = zv[0]; zr1 = zv[1]; zr2 = zv[2]; zr3 = zv[3];
    if (isdyn && rrow < 8) {
      *reinterpret_cast<uint2*>(&xb[rrow * 168 + 16 * wl + 4 * g]) =
          make_uint2(cvt_pk_bf16(zr0, zr1), cvt_pk_bf16(zr2, zr3));
    }
  }
  __syncthreads();

  // dyn L1 static frags (cols 96-159: ctx + zero pad)
  short8 xs[2];
  xs[0] = *reinterpret_cast<const short8*>(&xb[r8 * 168 + 96 + g * 8]);
  xs[1] = *reinterpret_cast<const short8*>(&xb[r8 * 168 + 128 + g * 8]);

  // per-lane output row pointer (dec L4, wave 4)
  float* po = out + ((size_t)(gb + r8) * N_) * 14 + 4 * g;

  for (int n = 0; n < N_; n++) {
    // phase A: L1 (dyn K=160: 3 dyn + 2 static frags; dec K=64: 2 frags of z in xb)
    if (isdyn)
      mlp_layer2<5, 3>(wA, wB, xs, b1t0, b1t1, A1t0, E1t0, A1t1, E1t1,
                       xb, h0, lnS, grpoff, wl, lane);
    else
      mlp_layer2<2, 2>(wA, wB, nullptr, b1t0, b1t1, A1t0, E1t0, A1t1, E1t1,
                       xb, h0, lnS, grpoff, wl, lane);
    // phase B: L2 ; phase C: L3 (identical for both groups)
    mlp_layer2<4, 4>(wA + 5, wB + 5, nullptr, b2t0, b2t1, A2t0, E2t0, A2t1, E2t1,
                     h0, h1, lnS, grpoff, wl, lane);
    mlp_layer2<4, 4>(wA + 9, wB + 9, nullptr, b3t0, b3t1, A3t0, E3t0, A3t1, E3t1,
                     h1, h0, lnS, grpoff, wl, lane);
    // phase D
    if (isdyn) {
      if (n < N_ - 1) {
        short8 xf4[4];
#pragma unroll
        for (int ks = 0; ks < 4; ks++)
          xf4[ks] = *reinterpret_cast<const short8*>(&h0[r8 * 168 + ks * 32 + g * 8]);
        floatx4 da = b4;
#pragma unroll
        for (int ks = 0; ks < 4; ks++)
          da = __builtin_amdgcn_mfma_f32_16x16x32_bf16(w4[ks], xf4[ks], da, 0, 0, 0);
        float dt = tl[r8][n + 1] - tl[r8][n];
        zr0 += dt * da[0]; zr1 += dt * da[1]; zr2 += dt * da[2]; zr3 += dt * da[3];
        if (rrow < 8) {
          *reinterpret_cast<uint2*>(&xb[rrow * 168 + 16 * wl + 4 * g]) =
              make_uint2(cvt_pk_bf16(zr0, zr1), cvt_pk_bf16(zr2, zr3));
        }
      }
    } else if (wv == 4) {
      // decoder L4: 14 output cols for the 8 rows, step n
      short8 xf4[4];
#pragma unroll
      for (int ks = 0; ks < 4; ks++)
        xf4[ks] = *reinterpret_cast<const short8*>(&h0[r8 * 168 + ks * 32 + g * 8]);
      floatx4 da = b4;
#pragma unroll
      for (int ks = 0; ks < 4; ks++)
        da = __builtin_amdgcn_mfma_f32_16x16x32_bf16(w4[ks], xf4[ks], da, 0, 0, 0);
      if (rrow < 8) {
        float* p = po + (size_t)n * 14;
        *reinterpret_cast<float2*>(p) = make_float2(da[0], da[1]);
        if (g < 3) *reinterpret_cast<float2*>(p + 2) = make_float2(da[2], da[3]);
      }
    } else {
      // waves 5-7: Fourier embedding for step n+1
      int t2 = tid - 320;
      if (t2 < 136 && n < N_ - 2) {
        int b = t2 / 17, j = t2 - b * 17;
        xb[b * 168 + 64 + j] = f2bf(four_emb(tl[b][n + 1], j));
      }
    }
    bar_lgkm();
  }
}

extern "C" void kernel_launch(void* const* d_in, const int* in_sizes, int n_in,
                              void* d_out, int out_size, void* d_ws, size_t ws_size,
                              hipStream_t stream) {
  const float* t = (const float*)d_in[0];
  const float* ctx = (const float*)d_in[1];
  const float* ce_w = (const float*)d_in[2];
  const float* ce_b = (const float*)d_in[3];
  const float* z0_w = (const float*)d_in[4];
  const float* z0_b = (const float*)d_in[5];
  const float* dw0 = (const float*)d_in[6];
  const float* db0 = (const float*)d_in[7];
  const float* dw1 = (const float*)d_in[8];
  const float* db1 = (const float*)d_in[9];
  const float* dw2 = (const float*)d_in[10];
  const float* db2 = (const float*)d_in[11];
  const float* dw3 = (const float*)d_in[12];
  const float* db3 = (const float*)d_in[13];
  const float* dg0 = (const float*)d_in[14];
  const float* dbe0 = (const float*)d_in[15];
  const float* dg1 = (const float*)d_in[16];
  const float* dbe1 = (const float*)d_in[17];
  const float* dg2 = (const float*)d_in[18];
  const float* dbe2 = (const float*)d_in[19];
  const float* ew0 = (const float*)d_in[20];
  const float* eb0 = (const float*)d_in[21];
  const float* ew1 = (const float*)d_in[22];
  const float* eb1 = (const float*)d_in[23];
  const float* ew2 = (const float*)d_in[24];
  const float* eb2 = (const float*)d_in[25];
  const float* ew3 = (const float*)d_in[26];
  const float* eb3 = (const float*)d_in[27];
  const float* eg0 = (const float*)d_in[28];
  const float* ebe0 = (const float*)d_in[29];
  const float* eg1 = (const float*)d_in[30];
  const float* ebe1 = (const float*)d_in[31];
  const float* eg2 = (const float*)d_in[32];
  const float* ebe2 = (const float*)d_in[33];
  float* out = (float*)d_out;

  char* ws = (char*)d_ws;
  u16* wdyn = (u16*)(ws + 0);        // 61440 elems = 122880 B
  u16* wdec = (u16*)(ws + 122880);   // 43008 elems =  86016 B

  rlp_pack_all<<<408, 256, 0, stream>>>(dw0, dw1, dw2, dw3, ew0, ew1, ew2, ew3, wdyn, wdec);

  rlp_fused<<<B_ / 8, 512, 0, stream>>>(t, wdyn, wdec, ctx, ce_w, ce_b, z0_w, z0_b,
      db0, db1, db2, db3, dg0, dbe0, dg1, dbe1, dg2, dbe2,
      eb0, eb1, eb2, eb3, eg0, ebe0, eg1, ebe1, eg2, ebe2, out);
}